// Round 1
// baseline (2099.298 us; speedup 1.0000x reference)
//
#include <hip/hip_runtime.h>

// ---------------------------------------------------------------------------
// DelayGNN stage: per layer t:
//   h1 = x_t @ W1[t];  h2 = x_{t-1} @ W2[t]  (t>0)
//   agg = a0 * scatter_add(norm1*h1[src1] -> dst1) + a1 * scatter_add(norm2*h2[src2] -> dst2)
//   x_{t+1} = l2normalize(x_t + relu(agg + a0*b1[t] + a1*b2[t]))
// norms: symmetric GCN normalization from degree counts (static across layers)
// ---------------------------------------------------------------------------

__global__ __launch_bounds__(64) void softmax_k(const float* __restrict__ alpha,
                                                float* __restrict__ a_soft, int Lnum) {
  int t = threadIdx.x;
  if (t >= Lnum) return;
  if (t == 0) { a_soft[0] = 1.0f; a_soft[1] = 0.0f; return; }
  float x0 = alpha[2 * t], x1 = alpha[2 * t + 1];
  float m = fmaxf(x0, x1);
  float e0 = expf(x0 - m), e1 = expf(x1 - m);
  float inv = 1.0f / (e0 + e1);
  a_soft[2 * t] = e0 * inv;
  a_soft[2 * t + 1] = e1 * inv;
}

__global__ __launch_bounds__(256) void deg_k(const int* __restrict__ src,
                                             const int* __restrict__ dst,
                                             float* __restrict__ dout,
                                             float* __restrict__ din, int E) {
  int i = threadIdx.x + blockIdx.x * 256;
  if (i >= E) return;
  unsafeAtomicAdd(&dout[src[i]], 1.0f);
  unsafeAtomicAdd(&din[dst[i]], 1.0f);
}

__global__ __launch_bounds__(256) void inv_k(float* __restrict__ d, int n) {
  int i = threadIdx.x + blockIdx.x * 256;
  if (i >= n) return;
  float v = d[i];
  d[i] = (v > 0.0f) ? rsqrtf(fmaxf(v, 1.0f)) : 0.0f;
}

// H[r][c] = sum_k X[r][k] * W[k][c],  D=128. 64 rows/block, K split in two
// 64-wide stages; W-stage 32KB + X-stage 16KB LDS = 48KB -> 3 blocks/CU.
__global__ __launch_bounds__(256) void gemm_k(const float* __restrict__ X,
                                              const float* __restrict__ W,
                                              float* __restrict__ H, int n) {
  __shared__ float wl[64 * 128];
  __shared__ float xl[64 * 64];
  int tid = threadIdx.x;
  int row0 = blockIdx.x * 64;
  int tc = tid & 31, tr = tid >> 5;  // tc: 32 col-threads x4 cols, tr: 8 row-threads x8 rows
  float4 acc[8];
#pragma unroll
  for (int i = 0; i < 8; ++i) acc[i] = make_float4(0.f, 0.f, 0.f, 0.f);

  for (int k0 = 0; k0 < 128; k0 += 64) {
    __syncthreads();
    const float4* W4 = (const float4*)W;
    float4* wl4 = (float4*)wl;
#pragma unroll
    for (int j = 0; j < 8; ++j) {        // 2048 float4 of W rows k0..k0+63
      int idx = tid + 256 * j;
      int kr = idx >> 5, cq = idx & 31;
      wl4[idx] = W4[(size_t)(k0 + kr) * 32 + cq];
    }
    float4* xl4 = (float4*)xl;
#pragma unroll
    for (int j = 0; j < 4; ++j) {        // 1024 float4 of X tile [64 rows][k0..k0+63]
      int idx = tid + 256 * j;
      int r = idx >> 4, kq = idx & 15;
      float4 v = make_float4(0.f, 0.f, 0.f, 0.f);
      if (row0 + r < n) v = *(const float4*)&X[(size_t)(row0 + r) * 128 + k0 + kq * 4];
      xl4[idx] = v;
    }
    __syncthreads();
#pragma unroll
    for (int kk = 0; kk < 64; ++kk) {
      float4 b = *(const float4*)&wl[kk * 128 + tc * 4];
#pragma unroll
      for (int i = 0; i < 8; ++i) {
        float a = xl[(tr * 8 + i) * 64 + kk];
        acc[i].x += a * b.x; acc[i].y += a * b.y;
        acc[i].z += a * b.z; acc[i].w += a * b.w;
      }
    }
  }
#pragma unroll
  for (int i = 0; i < 8; ++i) {
    int r = row0 + tr * 8 + i;
    if (r < n) *(float4*)&H[(size_t)r * 128 + tc * 4] = acc[i];
  }
}

// One wave per edge: AGG[dst] += a * inv_out[src]*inv_in[dst] * H[src]
__global__ __launch_bounds__(256) void scatter_k(const float* __restrict__ H,
                                                 float* __restrict__ AGG,
                                                 const int* __restrict__ src,
                                                 const int* __restrict__ dst,
                                                 const float* __restrict__ invo,
                                                 const float* __restrict__ invi,
                                                 const float* __restrict__ a_soft,
                                                 int aidx, int E) {
  int gw = (blockIdx.x * 256 + threadIdx.x) >> 6;
  int lane = threadIdx.x & 63;
  if (gw >= E) return;
  int s = src[gw], d = dst[gw];
  float sc = a_soft[aidx] * invo[s] * invi[d];
  float2 v = *(const float2*)&H[(size_t)s * 128 + lane * 2];
  float* out = &AGG[(size_t)d * 128 + lane * 2];
  unsafeAtomicAdd(out, v.x * sc);
  unsafeAtomicAdd(out + 1, v.y * sc);
}

// x_next = normalize(x + relu(agg + a0*b1 + a1*b2)); one wave per row
__global__ __launch_bounds__(256) void fin_k(const float* __restrict__ Xt,
                                             const float* __restrict__ AGG,
                                             const float* __restrict__ b1,
                                             const float* __restrict__ b2,
                                             const float* __restrict__ a_soft, int t,
                                             float* __restrict__ Xn, int n) {
  int w = threadIdx.x >> 6, lane = threadIdx.x & 63;
  int row = blockIdx.x * 4 + w;
  if (row >= n) return;
  float a0 = a_soft[2 * t], a1 = a_soft[2 * t + 1];
  int c = lane * 2;
  float bb0 = a0 * b1[c] + a1 * b2[c];
  float bb1 = a0 * b1[c + 1] + a1 * b2[c + 1];
  float2 x = *(const float2*)&Xt[(size_t)row * 128 + c];
  float2 g = *(const float2*)&AGG[(size_t)row * 128 + c];
  float vx = x.x + fmaxf(g.x + bb0, 0.0f);
  float vy = x.y + fmaxf(g.y + bb1, 0.0f);
  float ss = vx * vx + vy * vy;
#pragma unroll
  for (int off = 32; off >= 1; off >>= 1) ss += __shfl_xor(ss, off, 64);
  float inv = 1.0f / fmaxf(sqrtf(ss), 1e-12f);
  *(float2*)&Xn[(size_t)row * 128 + c] = make_float2(vx * inv, vy * inv);
}

extern "C" void kernel_launch(void* const* d_in, const int* in_sizes, int n_in,
                              void* d_out, int out_size, void* d_ws, size_t ws_size,
                              hipStream_t stream) {
  const float* x_in  = (const float*)d_in[0];
  const float* W1    = (const float*)d_in[1];
  const float* b1    = (const float*)d_in[2];
  const float* W2    = (const float*)d_in[3];
  const float* b2    = (const float*)d_in[4];
  const float* alpha = (const float*)d_in[5];
  const int* src1 = (const int*)d_in[6];
  const int* dst1 = (const int*)d_in[7];
  const int* src2 = (const int*)d_in[8];
  const int* dst2 = (const int*)d_in[9];

  int N = in_sizes[0] / 128;
  int Lnum = in_sizes[5] / 2;
  int E1 = in_sizes[6], E2 = in_sizes[8];

  size_t ND = (size_t)N * 128;
  float* xA   = (float*)d_ws;
  float* xB   = xA + ND;
  float* h1   = xB + ND;
  float* h2   = h1 + ND;
  float* agg  = h2 + ND;
  float* degs = agg + ND;              // 4*N floats: out1, in1, out2, in2
  float* a_soft = degs + 4 * (size_t)N;

  float* invo1 = degs;
  float* invi1 = degs + N;
  float* invo2 = degs + 2 * (size_t)N;
  float* invi2 = degs + 3 * (size_t)N;

  hipMemsetAsync(degs, 0, 4 * (size_t)N * sizeof(float), stream);
  softmax_k<<<1, 64, 0, stream>>>(alpha, a_soft, Lnum);
  deg_k<<<(E1 + 255) / 256, 256, 0, stream>>>(src1, dst1, invo1, invi1, E1);
  deg_k<<<(E2 + 255) / 256, 256, 0, stream>>>(src2, dst2, invo2, invi2, E2);
  inv_k<<<(4 * N + 255) / 256, 256, 0, stream>>>(degs, 4 * N);

  float* out = (float*)d_out;
  int gemm_grid = (N + 63) / 64;

  const float* prev = nullptr;
  const float* cur = x_in;
  for (int t = 0; t < Lnum; ++t) {
    float* nxt = (t == Lnum - 1) ? out : ((t & 1) ? xB : xA);
    gemm_k<<<gemm_grid, 256, 0, stream>>>(cur, W1 + (size_t)t * 16384, h1, N);
    if (t > 0)
      gemm_k<<<gemm_grid, 256, 0, stream>>>(prev, W2 + (size_t)t * 16384, h2, N);
    hipMemsetAsync(agg, 0, ND * sizeof(float), stream);
    scatter_k<<<(E1 + 3) / 4, 256, 0, stream>>>(h1, agg, src1, dst1, invo1, invi1,
                                                a_soft, 2 * t, E1);
    if (t > 0)
      scatter_k<<<(E2 + 3) / 4, 256, 0, stream>>>(h2, agg, src2, dst2, invo2, invi2,
                                                  a_soft, 2 * t + 1, E2);
    fin_k<<<(N + 3) / 4, 256, 0, stream>>>(cur, agg, b1 + (size_t)t * 128,
                                           b2 + (size_t)t * 128, a_soft, t, nxt, N);
    prev = cur;
    cur = nxt;
  }
}

// Round 2
// 851.350 us; speedup vs baseline: 2.4658x; 2.4658x over previous
//
#include <hip/hip_runtime.h>

// ---------------------------------------------------------------------------
// DelayGNN stage, CSR-gather formulation:
//   per layer t:
//     H1 = (x_t @ W1[t]) * (a0*invo1[row])        (scale folded into epilogue)
//     H2 = (x_{t-1} @ W2[t]) * (a1*invo2[row])    (t>0)
//     row r: agg = invi1[r]*sum_{e in CSR1[r]} H1[src_e]
//                + invi2[r]*sum_{e in CSR2[r]} H2[src_e]
//     x_{t+1}[r] = l2norm(x_t[r] + relu(agg + a0*b1[t] + a1*b2[t]))
// CSR built once per call from (src,dst) with counting sort.
// ---------------------------------------------------------------------------

__global__ __launch_bounds__(64) void softmax_k(const float* __restrict__ alpha,
                                                float* __restrict__ a_soft, int Lnum) {
  int t = threadIdx.x;
  if (t >= Lnum) return;
  if (t == 0) { a_soft[0] = 1.0f; a_soft[1] = 0.0f; return; }
  float x0 = alpha[2 * t], x1 = alpha[2 * t + 1];
  float m = fmaxf(x0, x1);
  float e0 = expf(x0 - m), e1 = expf(x1 - m);
  float inv = 1.0f / (e0 + e1);
  a_soft[2 * t] = e0 * inv;
  a_soft[2 * t + 1] = e1 * inv;
}

// degree counts (float for norm) + int counts for CSR
__global__ __launch_bounds__(256) void deg_k(const int* __restrict__ src,
                                             const int* __restrict__ dst,
                                             float* __restrict__ dout,
                                             float* __restrict__ din,
                                             int* __restrict__ cnt, int E) {
  int i = threadIdx.x + blockIdx.x * 256;
  if (i >= E) return;
  unsafeAtomicAdd(&dout[src[i]], 1.0f);
  unsafeAtomicAdd(&din[dst[i]], 1.0f);
  atomicAdd(&cnt[dst[i]], 1);
}

__global__ __launch_bounds__(256) void inv_k(float* __restrict__ d, int n) {
  int i = threadIdx.x + blockIdx.x * 256;
  if (i >= n) return;
  float v = d[i];
  d[i] = (v > 0.0f) ? rsqrtf(fmaxf(v, 1.0f)) : 0.0f;
}

// single-block exclusive scan over cnt[0..n) -> row_start[0..n], cursor copy
__global__ __launch_bounds__(1024) void scan_k(const int* __restrict__ cnt,
                                               int* __restrict__ row_start,
                                               int* __restrict__ cursor, int n) {
  __shared__ int sums[1024];
  int tid = threadIdx.x;
  int chunk = (n + 1023) / 1024;
  int lo = tid * chunk;
  int hi = lo + chunk; if (hi > n) hi = n; if (lo > n) lo = n;
  int s = 0;
  for (int i = lo; i < hi; ++i) s += cnt[i];
  sums[tid] = s;
  __syncthreads();
  for (int off = 1; off < 1024; off <<= 1) {
    int v = 0;
    if (tid >= off) v = sums[tid - off];
    __syncthreads();
    if (tid >= off) sums[tid] += v;
    __syncthreads();
  }
  int base = (tid == 0) ? 0 : sums[tid - 1];
  for (int i = lo; i < hi; ++i) {
    row_start[i] = base;
    cursor[i] = base;
    base += cnt[i];
  }
  if (tid == 1023) row_start[n] = sums[1023];
}

__global__ __launch_bounds__(256) void place_k(const int* __restrict__ src,
                                               const int* __restrict__ dst,
                                               int* __restrict__ cursor,
                                               int* __restrict__ esrc, int E) {
  int i = threadIdx.x + blockIdx.x * 256;
  if (i >= E) return;
  int slot = atomicAdd(&cursor[dst[i]], 1);
  esrc[slot] = src[i];
}

// H[r][c] = (sum_k X[r][k]*W[k][c]) * (a_soft[aidx]*invo[r]).  D=128.
__global__ __launch_bounds__(256) void gemm_k(const float* __restrict__ X,
                                              const float* __restrict__ W,
                                              float* __restrict__ H,
                                              const float* __restrict__ invo,
                                              const float* __restrict__ a_soft,
                                              int aidx, int n) {
  __shared__ float wl[64 * 128];
  __shared__ float xl[64 * 64];
  int tid = threadIdx.x;
  int row0 = blockIdx.x * 64;
  int tc = tid & 31, tr = tid >> 5;
  float4 acc[8];
#pragma unroll
  for (int i = 0; i < 8; ++i) acc[i] = make_float4(0.f, 0.f, 0.f, 0.f);

  for (int k0 = 0; k0 < 128; k0 += 64) {
    __syncthreads();
    const float4* W4 = (const float4*)W;
    float4* wl4 = (float4*)wl;
#pragma unroll
    for (int j = 0; j < 8; ++j) {
      int idx = tid + 256 * j;
      int kr = idx >> 5, cq = idx & 31;
      wl4[idx] = W4[(size_t)(k0 + kr) * 32 + cq];
    }
    float4* xl4 = (float4*)xl;
#pragma unroll
    for (int j = 0; j < 4; ++j) {
      int idx = tid + 256 * j;
      int r = idx >> 4, kq = idx & 15;
      float4 v = make_float4(0.f, 0.f, 0.f, 0.f);
      if (row0 + r < n) v = *(const float4*)&X[(size_t)(row0 + r) * 128 + k0 + kq * 4];
      xl4[idx] = v;
    }
    __syncthreads();
#pragma unroll
    for (int kk = 0; kk < 64; ++kk) {
      float4 b = *(const float4*)&wl[kk * 128 + tc * 4];
#pragma unroll
      for (int i = 0; i < 8; ++i) {
        float a = xl[(tr * 8 + i) * 64 + kk];
        acc[i].x += a * b.x; acc[i].y += a * b.y;
        acc[i].z += a * b.z; acc[i].w += a * b.w;
      }
    }
  }
  float as = a_soft[aidx];
#pragma unroll
  for (int i = 0; i < 8; ++i) {
    int r = row0 + tr * 8 + i;
    if (r < n) {
      float sc = as * invo[r];
      float4 v = make_float4(acc[i].x * sc, acc[i].y * sc, acc[i].z * sc, acc[i].w * sc);
      *(float4*)&H[(size_t)r * 128 + tc * 4] = v;
    }
  }
}

// fused gather + bias + relu + residual + l2norm; one wave per row
__global__ __launch_bounds__(256) void aggfin_k(
    const float* __restrict__ Xt,
    const float* __restrict__ H1, const float* __restrict__ H2,
    const int* __restrict__ rs1, const int* __restrict__ es1,
    const int* __restrict__ rs2, const int* __restrict__ es2,
    const float* __restrict__ invi1, const float* __restrict__ invi2,
    const float* __restrict__ b1, const float* __restrict__ b2,
    const float* __restrict__ a_soft, int t,
    float* __restrict__ Xn, int n, int hop2) {
  int w = threadIdx.x >> 6, lane = threadIdx.x & 63;
  int row = blockIdx.x * 4 + w;
  if (row >= n) return;
  int c = lane * 2;

  float gx = 0.f, gy = 0.f;
  {
    float ax = 0.f, ay = 0.f;
    int e0 = rs1[row], e1 = rs1[row + 1];
    for (int e = e0; e < e1; ++e) {
      int s = es1[e];
      float2 v = *(const float2*)&H1[(size_t)s * 128 + c];
      ax += v.x; ay += v.y;
    }
    float gi = invi1[row];
    gx = ax * gi; gy = ay * gi;
  }
  if (hop2) {
    float ax = 0.f, ay = 0.f;
    int e0 = rs2[row], e1 = rs2[row + 1];
    for (int e = e0; e < e1; ++e) {
      int s = es2[e];
      float2 v = *(const float2*)&H2[(size_t)s * 128 + c];
      ax += v.x; ay += v.y;
    }
    float gi = invi2[row];
    gx += ax * gi; gy += ay * gi;
  }

  float a0 = a_soft[2 * t], a1s = a_soft[2 * t + 1];
  float bb0 = a0 * b1[c] + a1s * b2[c];
  float bb1 = a0 * b1[c + 1] + a1s * b2[c + 1];
  float2 x = *(const float2*)&Xt[(size_t)row * 128 + c];
  float vx = x.x + fmaxf(gx + bb0, 0.0f);
  float vy = x.y + fmaxf(gy + bb1, 0.0f);
  float ss = vx * vx + vy * vy;
#pragma unroll
  for (int off = 32; off >= 1; off >>= 1) ss += __shfl_xor(ss, off, 64);
  float inv = 1.0f / fmaxf(sqrtf(ss), 1e-12f);
  *(float2*)&Xn[(size_t)row * 128 + c] = make_float2(vx * inv, vy * inv);
}

extern "C" void kernel_launch(void* const* d_in, const int* in_sizes, int n_in,
                              void* d_out, int out_size, void* d_ws, size_t ws_size,
                              hipStream_t stream) {
  const float* x_in  = (const float*)d_in[0];
  const float* W1    = (const float*)d_in[1];
  const float* b1    = (const float*)d_in[2];
  const float* W2    = (const float*)d_in[3];
  const float* b2    = (const float*)d_in[4];
  const float* alpha = (const float*)d_in[5];
  const int* src1 = (const int*)d_in[6];
  const int* dst1 = (const int*)d_in[7];
  const int* src2 = (const int*)d_in[8];
  const int* dst2 = (const int*)d_in[9];

  int N = in_sizes[0] / 128;
  int Lnum = in_sizes[5] / 2;
  int E1 = in_sizes[6], E2 = in_sizes[8];

  size_t ND = (size_t)N * 128;
  float* xA = (float*)d_ws;
  float* xB = xA + ND;
  float* h1 = xB + ND;
  float* h2 = h1 + ND;
  float* degs = h2 + ND;             // 4*N: invo1, invi1, invo2, invi2
  float* a_soft = degs + 4 * (size_t)N;
  int* ibase = (int*)(a_soft + 64);
  int* cnt1 = ibase;                 // N
  int* cnt2 = cnt1 + N;              // N
  int* rs1  = cnt2 + N;              // N+1
  int* rs2  = rs1 + N + 1;           // N+1
  int* cur1 = rs2 + N + 1;           // N
  int* cur2 = cur1 + N;              // N
  int* es1  = cur2 + N;              // E1
  int* es2  = es1 + E1;              // E2

  float* invo1 = degs;
  float* invi1 = degs + N;
  float* invo2 = degs + 2 * (size_t)N;
  float* invi2 = degs + 3 * (size_t)N;

  hipMemsetAsync(degs, 0, 4 * (size_t)N * sizeof(float), stream);
  hipMemsetAsync(cnt1, 0, 2 * (size_t)N * sizeof(int), stream);
  softmax_k<<<1, 64, 0, stream>>>(alpha, a_soft, Lnum);
  deg_k<<<(E1 + 255) / 256, 256, 0, stream>>>(src1, dst1, invo1, invi1, cnt1, E1);
  deg_k<<<(E2 + 255) / 256, 256, 0, stream>>>(src2, dst2, invo2, invi2, cnt2, E2);
  inv_k<<<(4 * N + 255) / 256, 256, 0, stream>>>(degs, 4 * N);
  scan_k<<<1, 1024, 0, stream>>>(cnt1, rs1, cur1, N);
  scan_k<<<1, 1024, 0, stream>>>(cnt2, rs2, cur2, N);
  place_k<<<(E1 + 255) / 256, 256, 0, stream>>>(src1, dst1, cur1, es1, E1);
  place_k<<<(E2 + 255) / 256, 256, 0, stream>>>(src2, dst2, cur2, es2, E2);

  float* out = (float*)d_out;
  int gemm_grid = (N + 63) / 64;
  int fin_grid = (N + 3) / 4;

  const float* prev = nullptr;
  const float* cur = x_in;
  for (int t = 0; t < Lnum; ++t) {
    float* nxt = (t == Lnum - 1) ? out : ((t & 1) ? xB : xA);
    gemm_k<<<gemm_grid, 256, 0, stream>>>(cur, W1 + (size_t)t * 16384, h1,
                                          invo1, a_soft, 2 * t, N);
    if (t > 0)
      gemm_k<<<gemm_grid, 256, 0, stream>>>(prev, W2 + (size_t)t * 16384, h2,
                                            invo2, a_soft, 2 * t + 1, N);
    aggfin_k<<<fin_grid, 256, 0, stream>>>(cur, h1, h2, rs1, es1, rs2, es2,
                                           invi1, invi2,
                                           b1 + (size_t)t * 128, b2 + (size_t)t * 128,
                                           a_soft, t, nxt, N, t > 0 ? 1 : 0);
    prev = cur;
    cur = nxt;
  }
}

// Round 3
// 615.448 us; speedup vs baseline: 3.4110x; 1.3833x over previous
//
#include <hip/hip_runtime.h>

// ---------------------------------------------------------------------------
// DelayGNN stage, CSR-gather formulation:
//   per layer t:
//     H1 = (x_t @ W1[t]) * (a0*invo1[row])        (scale folded into epilogue)
//     H2 = (x_{t-1} @ W2[t]) * (a1*invo2[row])    (t>0)
//     row r: agg = invi1[r]*sum_{e in CSR1[r]} H1[src_e]
//                + invi2[r]*sum_{e in CSR2[r]} H2[src_e]
//     x_{t+1}[r] = l2norm(x_t[r] + relu(agg + a0*b1[t] + a1*b2[t]))
// CSR built once per call; 3-phase multi-block scan (1024 elems/block).
// ---------------------------------------------------------------------------

__global__ __launch_bounds__(64) void softmax_k(const float* __restrict__ alpha,
                                                float* __restrict__ a_soft, int Lnum) {
  int t = threadIdx.x;
  if (t >= Lnum) return;
  if (t == 0) { a_soft[0] = 1.0f; a_soft[1] = 0.0f; return; }
  float x0 = alpha[2 * t], x1 = alpha[2 * t + 1];
  float m = fmaxf(x0, x1);
  float e0 = expf(x0 - m), e1 = expf(x1 - m);
  float inv = 1.0f / (e0 + e1);
  a_soft[2 * t] = e0 * inv;
  a_soft[2 * t + 1] = e1 * inv;
}

__global__ __launch_bounds__(256) void deg_k(const int* __restrict__ src,
                                             const int* __restrict__ dst,
                                             int* __restrict__ cnto,
                                             int* __restrict__ cnti, int E) {
  int i = threadIdx.x + blockIdx.x * 256;
  if (i >= E) return;
  atomicAdd(&cnto[src[i]], 1);
  atomicAdd(&cnti[dst[i]], 1);
}

// int degree -> rsqrt norm factor (deg>0 ? rsqrt(deg) : 0)
__global__ __launch_bounds__(256) void inv_k(const int* __restrict__ cnt,
                                             float* __restrict__ inv, int n) {
  int i = threadIdx.x + blockIdx.x * 256;
  if (i >= n) return;
  int v = cnt[i];
  inv[i] = (v > 0) ? rsqrtf((float)v) : 0.0f;
}

// phase A: per-block (1024 elems) sums
__global__ __launch_bounds__(256) void psum_k(const int* __restrict__ cnt,
                                              int* __restrict__ bsums, int n) {
  int base = blockIdx.x * 1024 + threadIdx.x * 4;
  int s = 0;
#pragma unroll
  for (int j = 0; j < 4; ++j) { int i = base + j; if (i < n) s += cnt[i]; }
#pragma unroll
  for (int off = 1; off < 64; off <<= 1) s += __shfl_xor(s, off, 64);
  __shared__ int ws[4];
  int lane = threadIdx.x & 63, w = threadIdx.x >> 6;
  if (lane == 0) ws[w] = s;
  __syncthreads();
  if (threadIdx.x == 0) bsums[blockIdx.x] = ws[0] + ws[1] + ws[2] + ws[3];
}

// phase B: exclusive scan of <=256 block sums (one block); writes total to row_start[n]
__global__ __launch_bounds__(256) void bscan_k(const int* __restrict__ bsums,
                                               int* __restrict__ boffs,
                                               int* __restrict__ row_start,
                                               int nb, int n) {
  __shared__ int sm[256];
  int tid = threadIdx.x;
  int v = (tid < nb) ? bsums[tid] : 0;
  sm[tid] = v;
  __syncthreads();
  for (int off = 1; off < 256; off <<= 1) {
    int u = (tid >= off) ? sm[tid - off] : 0;
    __syncthreads();
    sm[tid] += u;
    __syncthreads();
  }
  if (tid < nb) boffs[tid] = sm[tid] - v;
  if (tid == 255) row_start[n] = sm[255];
}

// phase C: per-block exclusive scan + apply block offset -> row_start, cursor
__global__ __launch_bounds__(256) void sapply_k(const int* __restrict__ cnt,
                                                const int* __restrict__ boffs,
                                                int* __restrict__ row_start,
                                                int* __restrict__ cursor, int n) {
  int lane = threadIdx.x & 63, w = threadIdx.x >> 6;
  int base = blockIdx.x * 1024 + threadIdx.x * 4;
  int c[4], s = 0;
#pragma unroll
  for (int j = 0; j < 4; ++j) { int i = base + j; c[j] = (i < n) ? cnt[i] : 0; s += c[j]; }
  int incl = s;
#pragma unroll
  for (int off = 1; off < 64; off <<= 1) {
    int u = __shfl_up(incl, off, 64);
    if (lane >= off) incl += u;
  }
  int excl = incl - s;
  __shared__ int ws[4];
  if (lane == 63) ws[w] = incl;
  __syncthreads();
  int woff = 0;
  for (int i = 0; i < w; ++i) woff += ws[i];
  int off0 = boffs[blockIdx.x] + woff + excl;
#pragma unroll
  for (int j = 0; j < 4; ++j) {
    int i = base + j;
    if (i < n) { row_start[i] = off0; cursor[i] = off0; off0 += c[j]; }
  }
}

__global__ __launch_bounds__(256) void place_k(const int* __restrict__ src,
                                               const int* __restrict__ dst,
                                               int* __restrict__ cursor,
                                               int* __restrict__ esrc, int E) {
  int i = threadIdx.x + blockIdx.x * 256;
  if (i >= E) return;
  int slot = atomicAdd(&cursor[dst[i]], 1);
  esrc[slot] = src[i];
}

// H[r][c] = (sum_k X[r][k]*W[k][c]) * (a_soft[aidx]*invo[r]).  D=128.
__global__ __launch_bounds__(256) void gemm_k(const float* __restrict__ X,
                                              const float* __restrict__ W,
                                              float* __restrict__ H,
                                              const float* __restrict__ invo,
                                              const float* __restrict__ a_soft,
                                              int aidx, int n) {
  __shared__ float wl[64 * 128];
  __shared__ float xl[64 * 64];
  int tid = threadIdx.x;
  int row0 = blockIdx.x * 64;
  int tc = tid & 31, tr = tid >> 5;
  float4 acc[8];
#pragma unroll
  for (int i = 0; i < 8; ++i) acc[i] = make_float4(0.f, 0.f, 0.f, 0.f);

  for (int k0 = 0; k0 < 128; k0 += 64) {
    __syncthreads();
    const float4* W4 = (const float4*)W;
    float4* wl4 = (float4*)wl;
#pragma unroll
    for (int j = 0; j < 8; ++j) {
      int idx = tid + 256 * j;
      int kr = idx >> 5, cq = idx & 31;
      wl4[idx] = W4[(size_t)(k0 + kr) * 32 + cq];
    }
    float4* xl4 = (float4*)xl;
#pragma unroll
    for (int j = 0; j < 4; ++j) {
      int idx = tid + 256 * j;
      int r = idx >> 4, kq = idx & 15;
      float4 v = make_float4(0.f, 0.f, 0.f, 0.f);
      if (row0 + r < n) v = *(const float4*)&X[(size_t)(row0 + r) * 128 + k0 + kq * 4];
      xl4[idx] = v;
    }
    __syncthreads();
#pragma unroll
    for (int kk = 0; kk < 64; ++kk) {
      float4 b = *(const float4*)&wl[kk * 128 + tc * 4];
#pragma unroll
      for (int i = 0; i < 8; ++i) {
        float a = xl[(tr * 8 + i) * 64 + kk];
        acc[i].x += a * b.x; acc[i].y += a * b.y;
        acc[i].z += a * b.z; acc[i].w += a * b.w;
      }
    }
  }
  float as = a_soft[aidx];
#pragma unroll
  for (int i = 0; i < 8; ++i) {
    int r = row0 + tr * 8 + i;
    if (r < n) {
      float sc = as * invo[r];
      float4 v = make_float4(acc[i].x * sc, acc[i].y * sc, acc[i].z * sc, acc[i].w * sc);
      *(float4*)&H[(size_t)r * 128 + tc * 4] = v;
    }
  }
}

// fused gather + bias + relu + residual + l2norm; one wave per row
__global__ __launch_bounds__(256) void aggfin_k(
    const float* __restrict__ Xt,
    const float* __restrict__ H1, const float* __restrict__ H2,
    const int* __restrict__ rs1, const int* __restrict__ es1,
    const int* __restrict__ rs2, const int* __restrict__ es2,
    const float* __restrict__ invi1, const float* __restrict__ invi2,
    const float* __restrict__ b1, const float* __restrict__ b2,
    const float* __restrict__ a_soft, int t,
    float* __restrict__ Xn, int n, int hop2) {
  int w = threadIdx.x >> 6, lane = threadIdx.x & 63;
  int row = blockIdx.x * 4 + w;
  if (row >= n) return;
  int c = lane * 2;

  float gx = 0.f, gy = 0.f;
  {
    float ax = 0.f, ay = 0.f;
    int e0 = rs1[row], e1 = rs1[row + 1];
    for (int e = e0; e < e1; ++e) {
      int s = es1[e];
      float2 v = *(const float2*)&H1[(size_t)s * 128 + c];
      ax += v.x; ay += v.y;
    }
    float gi = invi1[row];
    gx = ax * gi; gy = ay * gi;
  }
  if (hop2) {
    float ax = 0.f, ay = 0.f;
    int e0 = rs2[row], e1 = rs2[row + 1];
    for (int e = e0; e < e1; ++e) {
      int s = es2[e];
      float2 v = *(const float2*)&H2[(size_t)s * 128 + c];
      ax += v.x; ay += v.y;
    }
    float gi = invi2[row];
    gx += ax * gi; gy += ay * gi;
  }

  float a0 = a_soft[2 * t], a1s = a_soft[2 * t + 1];
  float bb0 = a0 * b1[c] + a1s * b2[c];
  float bb1 = a0 * b1[c + 1] + a1s * b2[c + 1];
  float2 x = *(const float2*)&Xt[(size_t)row * 128 + c];
  float vx = x.x + fmaxf(gx + bb0, 0.0f);
  float vy = x.y + fmaxf(gy + bb1, 0.0f);
  float ss = vx * vx + vy * vy;
#pragma unroll
  for (int off = 32; off >= 1; off >>= 1) ss += __shfl_xor(ss, off, 64);
  float inv = 1.0f / fmaxf(sqrtf(ss), 1e-12f);
  *(float2*)&Xn[(size_t)row * 128 + c] = make_float2(vx * inv, vy * inv);
}

extern "C" void kernel_launch(void* const* d_in, const int* in_sizes, int n_in,
                              void* d_out, int out_size, void* d_ws, size_t ws_size,
                              hipStream_t stream) {
  const float* x_in  = (const float*)d_in[0];
  const float* W1    = (const float*)d_in[1];
  const float* b1    = (const float*)d_in[2];
  const float* W2    = (const float*)d_in[3];
  const float* b2    = (const float*)d_in[4];
  const float* alpha = (const float*)d_in[5];
  const int* src1 = (const int*)d_in[6];
  const int* dst1 = (const int*)d_in[7];
  const int* src2 = (const int*)d_in[8];
  const int* dst2 = (const int*)d_in[9];

  int N = in_sizes[0] / 128;
  int Lnum = in_sizes[5] / 2;
  int E1 = in_sizes[6], E2 = in_sizes[8];

  size_t ND = (size_t)N * 128;
  float* xA = (float*)d_ws;
  float* xB = xA + ND;
  float* h1 = xB + ND;
  float* h2 = h1 + ND;
  float* degs = h2 + ND;             // 4*N floats: invo1, invi1, invo2, invi2
  float* a_soft = degs + 4 * (size_t)N;
  int* ibase = (int*)(a_soft + 64);
  int* cnto1 = ibase;                // N   (order must match degs: o1,i1,o2,i2)
  int* cnti1 = cnto1 + N;            // N
  int* cnto2 = cnti1 + N;            // N
  int* cnti2 = cnto2 + N;            // N
  int* rs1   = cnti2 + N;            // N+1
  int* rs2   = rs1 + N + 1;          // N+1
  int* cur1  = rs2 + N + 1;          // N
  int* cur2  = cur1 + N;             // N
  int* bsum  = cur2 + N;             // 256
  int* boff  = bsum + 256;           // 256
  int* es1   = boff + 256;           // E1
  int* es2   = es1 + E1;             // E2

  float* invo1 = degs;
  float* invi1 = degs + N;
  float* invo2 = degs + 2 * (size_t)N;
  float* invi2 = degs + 3 * (size_t)N;

  int nb = (N + 1023) / 1024;

  hipMemsetAsync(cnto1, 0, 4 * (size_t)N * sizeof(int), stream);
  softmax_k<<<1, 64, 0, stream>>>(alpha, a_soft, Lnum);
  deg_k<<<(E1 + 255) / 256, 256, 0, stream>>>(src1, dst1, cnto1, cnti1, E1);
  deg_k<<<(E2 + 255) / 256, 256, 0, stream>>>(src2, dst2, cnto2, cnti2, E2);
  inv_k<<<(4 * N + 255) / 256, 256, 0, stream>>>(cnto1, degs, 4 * N);
  // CSR hop1
  psum_k<<<nb, 256, 0, stream>>>(cnti1, bsum, N);
  bscan_k<<<1, 256, 0, stream>>>(bsum, boff, rs1, nb, N);
  sapply_k<<<nb, 256, 0, stream>>>(cnti1, boff, rs1, cur1, N);
  // CSR hop2
  psum_k<<<nb, 256, 0, stream>>>(cnti2, bsum, N);
  bscan_k<<<1, 256, 0, stream>>>(bsum, boff, rs2, nb, N);
  sapply_k<<<nb, 256, 0, stream>>>(cnti2, boff, rs2, cur2, N);

  place_k<<<(E1 + 255) / 256, 256, 0, stream>>>(src1, dst1, cur1, es1, E1);
  place_k<<<(E2 + 255) / 256, 256, 0, stream>>>(src2, dst2, cur2, es2, E2);

  float* out = (float*)d_out;
  int gemm_grid = (N + 63) / 64;
  int fin_grid = (N + 3) / 4;

  const float* prev = nullptr;
  const float* cur = x_in;
  for (int t = 0; t < Lnum; ++t) {
    float* nxt = (t == Lnum - 1) ? out : ((t & 1) ? xB : xA);
    gemm_k<<<gemm_grid, 256, 0, stream>>>(cur, W1 + (size_t)t * 16384, h1,
                                          invo1, a_soft, 2 * t, N);
    if (t > 0)
      gemm_k<<<gemm_grid, 256, 0, stream>>>(prev, W2 + (size_t)t * 16384, h2,
                                            invo2, a_soft, 2 * t + 1, N);
    aggfin_k<<<fin_grid, 256, 0, stream>>>(cur, h1, h2, rs1, es1, rs2, es2,
                                           invi1, invi2,
                                           b1 + (size_t)t * 128, b2 + (size_t)t * 128,
                                           a_soft, t, nxt, N, t > 0 ? 1 : 0);
    prev = cur;
    cur = nxt;
  }
}

// Round 4
// 527.726 us; speedup vs baseline: 3.9780x; 1.1662x over previous
//
#include <hip/hip_runtime.h>

// ---------------------------------------------------------------------------
// DelayGNN stage, CSR-gather formulation, bf16 message buffers:
//   per layer t:
//     H1 = bf16((x_t @ W1[t]) * (a0*invo1[row]))
//     H2 = bf16((x_{t-1} @ W2[t]) * (a1*invo2[row]))    (t>0)
//     row r: agg = invi1[r]*sum_{e in CSR1[r]} H1[src_e]
//                + invi2[r]*sum_{e in CSR2[r]} H2[src_e]
//     x_{t+1}[r] = l2norm(x_t[r] + relu(agg + a0*b1[t] + a1*b2[t]))
// ---------------------------------------------------------------------------

typedef unsigned short u16;

__device__ inline float bf2f(u16 u) {
  unsigned int v = ((unsigned int)u) << 16;
  return __uint_as_float(v);
}
__device__ inline u16 f2bf(float f) {  // RNE
  unsigned int u = __float_as_uint(f);
  unsigned int r = (u + 0x7fff + ((u >> 16) & 1)) >> 16;
  return (u16)r;
}

__global__ __launch_bounds__(64) void softmax_k(const float* __restrict__ alpha,
                                                float* __restrict__ a_soft, int Lnum) {
  int t = threadIdx.x;
  if (t >= Lnum) return;
  if (t == 0) { a_soft[0] = 1.0f; a_soft[1] = 0.0f; return; }
  float x0 = alpha[2 * t], x1 = alpha[2 * t + 1];
  float m = fmaxf(x0, x1);
  float e0 = expf(x0 - m), e1 = expf(x1 - m);
  float inv = 1.0f / (e0 + e1);
  a_soft[2 * t] = e0 * inv;
  a_soft[2 * t + 1] = e1 * inv;
}

__global__ __launch_bounds__(256) void deg_k(const int* __restrict__ src,
                                             const int* __restrict__ dst,
                                             int* __restrict__ cnto,
                                             int* __restrict__ cnti, int E) {
  int i = threadIdx.x + blockIdx.x * 256;
  if (i >= E) return;
  atomicAdd(&cnto[src[i]], 1);
  atomicAdd(&cnti[dst[i]], 1);
}

__global__ __launch_bounds__(256) void inv_k(const int* __restrict__ cnt,
                                             float* __restrict__ inv, int n) {
  int i = threadIdx.x + blockIdx.x * 256;
  if (i >= n) return;
  int v = cnt[i];
  inv[i] = (v > 0) ? rsqrtf((float)v) : 0.0f;
}

__global__ __launch_bounds__(256) void psum_k(const int* __restrict__ cnt,
                                              int* __restrict__ bsums, int n) {
  int base = blockIdx.x * 1024 + threadIdx.x * 4;
  int s = 0;
#pragma unroll
  for (int j = 0; j < 4; ++j) { int i = base + j; if (i < n) s += cnt[i]; }
#pragma unroll
  for (int off = 1; off < 64; off <<= 1) s += __shfl_xor(s, off, 64);
  __shared__ int ws[4];
  int lane = threadIdx.x & 63, w = threadIdx.x >> 6;
  if (lane == 0) ws[w] = s;
  __syncthreads();
  if (threadIdx.x == 0) bsums[blockIdx.x] = ws[0] + ws[1] + ws[2] + ws[3];
}

__global__ __launch_bounds__(256) void bscan_k(const int* __restrict__ bsums,
                                               int* __restrict__ boffs,
                                               int* __restrict__ row_start,
                                               int nb, int n) {
  __shared__ int sm[256];
  int tid = threadIdx.x;
  int v = (tid < nb) ? bsums[tid] : 0;
  sm[tid] = v;
  __syncthreads();
  for (int off = 1; off < 256; off <<= 1) {
    int u = (tid >= off) ? sm[tid - off] : 0;
    __syncthreads();
    sm[tid] += u;
    __syncthreads();
  }
  if (tid < nb) boffs[tid] = sm[tid] - v;
  if (tid == 255) row_start[n] = sm[255];
}

__global__ __launch_bounds__(256) void sapply_k(const int* __restrict__ cnt,
                                                const int* __restrict__ boffs,
                                                int* __restrict__ row_start,
                                                int* __restrict__ cursor, int n) {
  int lane = threadIdx.x & 63, w = threadIdx.x >> 6;
  int base = blockIdx.x * 1024 + threadIdx.x * 4;
  int c[4], s = 0;
#pragma unroll
  for (int j = 0; j < 4; ++j) { int i = base + j; c[j] = (i < n) ? cnt[i] : 0; s += c[j]; }
  int incl = s;
#pragma unroll
  for (int off = 1; off < 64; off <<= 1) {
    int u = __shfl_up(incl, off, 64);
    if (lane >= off) incl += u;
  }
  int excl = incl - s;
  __shared__ int ws[4];
  if (lane == 63) ws[w] = incl;
  __syncthreads();
  int woff = 0;
  for (int i = 0; i < w; ++i) woff += ws[i];
  int off0 = boffs[blockIdx.x] + woff + excl;
#pragma unroll
  for (int j = 0; j < 4; ++j) {
    int i = base + j;
    if (i < n) { row_start[i] = off0; cursor[i] = off0; off0 += c[j]; }
  }
}

__global__ __launch_bounds__(256) void place_k(const int* __restrict__ src,
                                               const int* __restrict__ dst,
                                               int* __restrict__ cursor,
                                               int* __restrict__ esrc, int E) {
  int i = threadIdx.x + blockIdx.x * 256;
  if (i >= E) return;
  int slot = atomicAdd(&cursor[dst[i]], 1);
  esrc[slot] = src[i];
}

// H[r][c] = bf16((sum_k X[r][k]*W[k][c]) * (a_soft[aidx]*invo[r])).  D=128.
__global__ __launch_bounds__(256) void gemm_k(const float* __restrict__ X,
                                              const float* __restrict__ W,
                                              u16* __restrict__ H,
                                              const float* __restrict__ invo,
                                              const float* __restrict__ a_soft,
                                              int aidx, int n) {
  __shared__ float wl[64 * 128];
  __shared__ float xl[64 * 64];
  int tid = threadIdx.x;
  int row0 = blockIdx.x * 64;
  int tc = tid & 31, tr = tid >> 5;
  float4 acc[8];
#pragma unroll
  for (int i = 0; i < 8; ++i) acc[i] = make_float4(0.f, 0.f, 0.f, 0.f);

  for (int k0 = 0; k0 < 128; k0 += 64) {
    __syncthreads();
    const float4* W4 = (const float4*)W;
    float4* wl4 = (float4*)wl;
#pragma unroll
    for (int j = 0; j < 8; ++j) {
      int idx = tid + 256 * j;
      int kr = idx >> 5, cq = idx & 31;
      wl4[idx] = W4[(size_t)(k0 + kr) * 32 + cq];
    }
    float4* xl4 = (float4*)xl;
#pragma unroll
    for (int j = 0; j < 4; ++j) {
      int idx = tid + 256 * j;
      int r = idx >> 4, kq = idx & 15;
      float4 v = make_float4(0.f, 0.f, 0.f, 0.f);
      if (row0 + r < n) v = *(const float4*)&X[(size_t)(row0 + r) * 128 + k0 + kq * 4];
      xl4[idx] = v;
    }
    __syncthreads();
#pragma unroll
    for (int kk = 0; kk < 64; ++kk) {
      float4 b = *(const float4*)&wl[kk * 128 + tc * 4];
#pragma unroll
      for (int i = 0; i < 8; ++i) {
        float a = xl[(tr * 8 + i) * 64 + kk];
        acc[i].x += a * b.x; acc[i].y += a * b.y;
        acc[i].z += a * b.z; acc[i].w += a * b.w;
      }
    }
  }
  float as = a_soft[aidx];
#pragma unroll
  for (int i = 0; i < 8; ++i) {
    int r = row0 + tr * 8 + i;
    if (r < n) {
      float sc = as * invo[r];
      ushort4 o;
      o.x = f2bf(acc[i].x * sc); o.y = f2bf(acc[i].y * sc);
      o.z = f2bf(acc[i].z * sc); o.w = f2bf(acc[i].w * sc);
      *(ushort4*)&H[(size_t)r * 128 + tc * 4] = o;
    }
  }
}

// fused gather(bf16) + bias + relu + residual + l2norm; one wave per row.
// Lane layout: col = (lane&31)*4 .. +3 ; half = lane>>5 processes edges of
// matching parity (2 edge-rows in flight per wave), combined via shfl_xor(32).
__global__ __launch_bounds__(256) void aggfin_k(
    const float* __restrict__ Xt,
    const u16* __restrict__ H1, const u16* __restrict__ H2,
    const int* __restrict__ rs1, const int* __restrict__ es1,
    const int* __restrict__ rs2, const int* __restrict__ es2,
    const float* __restrict__ invi1, const float* __restrict__ invi2,
    const float* __restrict__ b1, const float* __restrict__ b2,
    const float* __restrict__ a_soft, int t,
    float* __restrict__ Xn, int n, int hop2) {
  int w = threadIdx.x >> 6, lane = threadIdx.x & 63;
  int row = blockIdx.x * 4 + w;
  if (row >= n) return;
  int half = lane >> 5;
  int cl = (lane & 31) * 4;

  float t0 = 0.f, t1 = 0.f, t2 = 0.f, t3 = 0.f;
  {
    float a0 = 0.f, a1 = 0.f, a2 = 0.f, a3 = 0.f;
    int e0 = rs1[row], e1 = rs1[row + 1];
    for (int e = e0 + half; e < e1; e += 2) {
      int s = es1[e];
      ushort4 h = *(const ushort4*)&H1[(size_t)s * 128 + cl];
      a0 += bf2f(h.x); a1 += bf2f(h.y); a2 += bf2f(h.z); a3 += bf2f(h.w);
    }
    float gi = invi1[row];
    t0 = a0 * gi; t1 = a1 * gi; t2 = a2 * gi; t3 = a3 * gi;
  }
  if (hop2) {
    float a0 = 0.f, a1 = 0.f, a2 = 0.f, a3 = 0.f;
    int e0 = rs2[row], e1 = rs2[row + 1];
    for (int e = e0 + half; e < e1; e += 2) {
      int s = es2[e];
      ushort4 h = *(const ushort4*)&H2[(size_t)s * 128 + cl];
      a0 += bf2f(h.x); a1 += bf2f(h.y); a2 += bf2f(h.z); a3 += bf2f(h.w);
    }
    float gi = invi2[row];
    t0 += a0 * gi; t1 += a1 * gi; t2 += a2 * gi; t3 += a3 * gi;
  }
  // combine even/odd edge halves (both halves end with identical values)
  t0 += __shfl_xor(t0, 32, 64);
  t1 += __shfl_xor(t1, 32, 64);
  t2 += __shfl_xor(t2, 32, 64);
  t3 += __shfl_xor(t3, 32, 64);

  float a0s = a_soft[2 * t], a1s = a_soft[2 * t + 1];
  float4 bv1 = *(const float4*)&b1[cl];
  float4 bv2 = *(const float4*)&b2[cl];
  float4 x = *(const float4*)&Xt[(size_t)row * 128 + cl];
  float v0 = x.x + fmaxf(t0 + a0s * bv1.x + a1s * bv2.x, 0.f);
  float v1 = x.y + fmaxf(t1 + a0s * bv1.y + a1s * bv2.y, 0.f);
  float v2 = x.z + fmaxf(t2 + a0s * bv1.z + a1s * bv2.z, 0.f);
  float v3 = x.w + fmaxf(t3 + a0s * bv1.w + a1s * bv2.w, 0.f);
  float ss = v0 * v0 + v1 * v1 + v2 * v2 + v3 * v3;
#pragma unroll
  for (int off = 16; off >= 1; off >>= 1) ss += __shfl_xor(ss, off, 64);
  float inv = 1.0f / fmaxf(sqrtf(ss), 1e-12f);
  if (half == 0)
    *(float4*)&Xn[(size_t)row * 128 + cl] =
        make_float4(v0 * inv, v1 * inv, v2 * inv, v3 * inv);
}

extern "C" void kernel_launch(void* const* d_in, const int* in_sizes, int n_in,
                              void* d_out, int out_size, void* d_ws, size_t ws_size,
                              hipStream_t stream) {
  const float* x_in  = (const float*)d_in[0];
  const float* W1    = (const float*)d_in[1];
  const float* b1    = (const float*)d_in[2];
  const float* W2    = (const float*)d_in[3];
  const float* b2    = (const float*)d_in[4];
  const float* alpha = (const float*)d_in[5];
  const int* src1 = (const int*)d_in[6];
  const int* dst1 = (const int*)d_in[7];
  const int* src2 = (const int*)d_in[8];
  const int* dst2 = (const int*)d_in[9];

  int N = in_sizes[0] / 128;
  int Lnum = in_sizes[5] / 2;
  int E1 = in_sizes[6], E2 = in_sizes[8];

  size_t ND = (size_t)N * 128;
  float* xA = (float*)d_ws;
  float* xB = xA + ND;
  u16* h1 = (u16*)(xB + ND);
  u16* h2 = h1 + ND;
  float* degs = (float*)(h2 + ND);   // 4*N floats: invo1, invi1, invo2, invi2
  float* a_soft = degs + 4 * (size_t)N;
  int* ibase = (int*)(a_soft + 64);
  int* cnto1 = ibase;                // N   (order must match degs: o1,i1,o2,i2)
  int* cnti1 = cnto1 + N;            // N
  int* cnto2 = cnti1 + N;            // N
  int* cnti2 = cnto2 + N;            // N
  int* rs1   = cnti2 + N;            // N+1
  int* rs2   = rs1 + N + 1;          // N+1
  int* cur1  = rs2 + N + 1;          // N
  int* cur2  = cur1 + N;             // N
  int* bsum  = cur2 + N;             // 256
  int* boff  = bsum + 256;           // 256
  int* es1   = boff + 256;           // E1
  int* es2   = es1 + E1;             // E2

  float* invo1 = degs;
  float* invi1 = degs + N;
  float* invo2 = degs + 2 * (size_t)N;
  float* invi2 = degs + 3 * (size_t)N;

  int nb = (N + 1023) / 1024;

  hipMemsetAsync(cnto1, 0, 4 * (size_t)N * sizeof(int), stream);
  softmax_k<<<1, 64, 0, stream>>>(alpha, a_soft, Lnum);
  deg_k<<<(E1 + 255) / 256, 256, 0, stream>>>(src1, dst1, cnto1, cnti1, E1);
  deg_k<<<(E2 + 255) / 256, 256, 0, stream>>>(src2, dst2, cnto2, cnti2, E2);
  inv_k<<<(4 * N + 255) / 256, 256, 0, stream>>>(cnto1, degs, 4 * N);
  psum_k<<<nb, 256, 0, stream>>>(cnti1, bsum, N);
  bscan_k<<<1, 256, 0, stream>>>(bsum, boff, rs1, nb, N);
  sapply_k<<<nb, 256, 0, stream>>>(cnti1, boff, rs1, cur1, N);
  psum_k<<<nb, 256, 0, stream>>>(cnti2, bsum, N);
  bscan_k<<<1, 256, 0, stream>>>(bsum, boff, rs2, nb, N);
  sapply_k<<<nb, 256, 0, stream>>>(cnti2, boff, rs2, cur2, N);
  place_k<<<(E1 + 255) / 256, 256, 0, stream>>>(src1, dst1, cur1, es1, E1);
  place_k<<<(E2 + 255) / 256, 256, 0, stream>>>(src2, dst2, cur2, es2, E2);

  float* out = (float*)d_out;
  int gemm_grid = (N + 63) / 64;
  int fin_grid = (N + 3) / 4;

  const float* prev = nullptr;
  const float* cur = x_in;
  for (int t = 0; t < Lnum; ++t) {
    float* nxt = (t == Lnum - 1) ? out : ((t & 1) ? xB : xA);
    gemm_k<<<gemm_grid, 256, 0, stream>>>(cur, W1 + (size_t)t * 16384, h1,
                                          invo1, a_soft, 2 * t, N);
    if (t > 0)
      gemm_k<<<gemm_grid, 256, 0, stream>>>(prev, W2 + (size_t)t * 16384, h2,
                                            invo2, a_soft, 2 * t + 1, N);
    aggfin_k<<<fin_grid, 256, 0, stream>>>(cur, h1, h2, rs1, es1, rs2, es2,
                                           invi1, invi2,
                                           b1 + (size_t)t * 128, b2 + (size_t)t * 128,
                                           a_soft, t, nxt, N, t > 0 ? 1 : 0);
    prev = cur;
    cur = nxt;
  }
}

// Round 5
// 456.835 us; speedup vs baseline: 4.5953x; 1.1552x over previous
//
#include <hip/hip_runtime.h>

// ---------------------------------------------------------------------------
// DelayGNN stage, CSR-gather + bf16-MFMA GEMM:
//   Wt = bf16(W^T) per layer/hop (prep once per call)
//   H1 = bf16((x_t @ W1[t]) * (a0*invo1[row]))       via mfma_f32_16x16x32_bf16
//   H2 = bf16((x_{t-1} @ W2[t]) * (a1*invo2[row]))   (t>0)
//   row r: agg = invi1[r]*sum_CSR1 H1[src] + invi2[r]*sum_CSR2 H2[src]
//   x_{t+1}[r] = l2norm(x_t[r] + relu(agg + a0*b1[t] + a1*b2[t]))
// ---------------------------------------------------------------------------

typedef unsigned short u16;
typedef __attribute__((ext_vector_type(8))) short short8;   // 8 bf16 (4 VGPR)
typedef __attribute__((ext_vector_type(4))) float f32x4;    // MFMA accum

__device__ inline float bf2f(u16 u) {
  unsigned int v = ((unsigned int)u) << 16;
  return __uint_as_float(v);
}
__device__ inline u16 f2bf(float f) {  // RNE
  unsigned int u = __float_as_uint(f);
  unsigned int r = (u + 0x7fff + ((u >> 16) & 1)) >> 16;
  return (u16)r;
}

__global__ __launch_bounds__(64) void softmax_k(const float* __restrict__ alpha,
                                                float* __restrict__ a_soft, int Lnum) {
  int t = threadIdx.x;
  if (t >= Lnum) return;
  if (t == 0) { a_soft[0] = 1.0f; a_soft[1] = 0.0f; return; }
  float x0 = alpha[2 * t], x1 = alpha[2 * t + 1];
  float m = fmaxf(x0, x1);
  float e0 = expf(x0 - m), e1 = expf(x1 - m);
  float inv = 1.0f / (e0 + e1);
  a_soft[2 * t] = e0 * inv;
  a_soft[2 * t + 1] = e1 * inv;
}

// W [k][n] fp32 -> Wt [n][k] bf16, all 2*Lnum matrices
__global__ __launch_bounds__(256) void prep_w_k(const float* __restrict__ W1,
                                                const float* __restrict__ W2,
                                                u16* __restrict__ Wt1,
                                                u16* __restrict__ Wt2, int Lnum) {
  int id = blockIdx.x * 256 + threadIdx.x;
  int per = 128 * 32;
  int mat = id / per, rem = id - mat * per;
  if (mat >= 2 * Lnum) return;
  int k = rem >> 5, n4 = (rem & 31) * 4;
  const float* W = (mat < Lnum) ? (W1 + (size_t)mat * 16384)
                                : (W2 + (size_t)(mat - Lnum) * 16384);
  u16* Wt = (mat < Lnum) ? (Wt1 + (size_t)mat * 16384)
                         : (Wt2 + (size_t)(mat - Lnum) * 16384);
  float4 v = *(const float4*)&W[k * 128 + n4];
  Wt[(size_t)(n4 + 0) * 128 + k] = f2bf(v.x);
  Wt[(size_t)(n4 + 1) * 128 + k] = f2bf(v.y);
  Wt[(size_t)(n4 + 2) * 128 + k] = f2bf(v.z);
  Wt[(size_t)(n4 + 3) * 128 + k] = f2bf(v.w);
}

__global__ __launch_bounds__(256) void deg_k(const int* __restrict__ src,
                                             const int* __restrict__ dst,
                                             int* __restrict__ cnto,
                                             int* __restrict__ cnti, int E) {
  int i = threadIdx.x + blockIdx.x * 256;
  if (i >= E) return;
  atomicAdd(&cnto[src[i]], 1);
  atomicAdd(&cnti[dst[i]], 1);
}

__global__ __launch_bounds__(256) void inv_k(const int* __restrict__ cnt,
                                             float* __restrict__ inv, int n) {
  int i = threadIdx.x + blockIdx.x * 256;
  if (i >= n) return;
  int v = cnt[i];
  inv[i] = (v > 0) ? rsqrtf((float)v) : 0.0f;
}

__global__ __launch_bounds__(256) void psum_k(const int* __restrict__ cnt,
                                              int* __restrict__ bsums, int n) {
  int base = blockIdx.x * 1024 + threadIdx.x * 4;
  int s = 0;
#pragma unroll
  for (int j = 0; j < 4; ++j) { int i = base + j; if (i < n) s += cnt[i]; }
#pragma unroll
  for (int off = 1; off < 64; off <<= 1) s += __shfl_xor(s, off, 64);
  __shared__ int ws[4];
  int lane = threadIdx.x & 63, w = threadIdx.x >> 6;
  if (lane == 0) ws[w] = s;
  __syncthreads();
  if (threadIdx.x == 0) bsums[blockIdx.x] = ws[0] + ws[1] + ws[2] + ws[3];
}

__global__ __launch_bounds__(256) void bscan_k(const int* __restrict__ bsums,
                                               int* __restrict__ boffs,
                                               int* __restrict__ row_start,
                                               int nb, int n) {
  __shared__ int sm[256];
  int tid = threadIdx.x;
  int v = (tid < nb) ? bsums[tid] : 0;
  sm[tid] = v;
  __syncthreads();
  for (int off = 1; off < 256; off <<= 1) {
    int u = (tid >= off) ? sm[tid - off] : 0;
    __syncthreads();
    sm[tid] += u;
    __syncthreads();
  }
  if (tid < nb) boffs[tid] = sm[tid] - v;
  if (tid == 255) row_start[n] = sm[255];
}

__global__ __launch_bounds__(256) void sapply_k(const int* __restrict__ cnt,
                                                const int* __restrict__ boffs,
                                                int* __restrict__ row_start,
                                                int* __restrict__ cursor, int n) {
  int lane = threadIdx.x & 63, w = threadIdx.x >> 6;
  int base = blockIdx.x * 1024 + threadIdx.x * 4;
  int c[4], s = 0;
#pragma unroll
  for (int j = 0; j < 4; ++j) { int i = base + j; c[j] = (i < n) ? cnt[i] : 0; s += c[j]; }
  int incl = s;
#pragma unroll
  for (int off = 1; off < 64; off <<= 1) {
    int u = __shfl_up(incl, off, 64);
    if (lane >= off) incl += u;
  }
  int excl = incl - s;
  __shared__ int ws[4];
  if (lane == 63) ws[w] = incl;
  __syncthreads();
  int woff = 0;
  for (int i = 0; i < w; ++i) woff += ws[i];
  int off0 = boffs[blockIdx.x] + woff + excl;
#pragma unroll
  for (int j = 0; j < 4; ++j) {
    int i = base + j;
    if (i < n) { row_start[i] = off0; cursor[i] = off0; off0 += c[j]; }
  }
}

__global__ __launch_bounds__(256) void place_k(const int* __restrict__ src,
                                               const int* __restrict__ dst,
                                               int* __restrict__ cursor,
                                               int* __restrict__ esrc, int E) {
  int i = threadIdx.x + blockIdx.x * 256;
  if (i >= E) return;
  int slot = atomicAdd(&cursor[dst[i]], 1);
  esrc[slot] = src[i];
}

// H[r][c] = bf16((X[r][:] @ W[:, c]) * (a_soft[aidx]*invo[r])) via bf16 MFMA.
// Block: 64 rows x 128 cols, 4 waves (16 rows each), 8 col-frags, 4 k-steps.
// A: X staged fp32->bf16 in LDS [64][136] (+8 pad -> 2-way bank alias, free).
// B: Wt [n][k] bf16 global (L2-resident, 32KB/matrix), 16B loads.
// C/D layout (m89-verified): col=lane&15, row=(lane>>4)*4+reg.
__global__ __launch_bounds__(256) void gemm_mfma_k(
    const float* __restrict__ X, const u16* __restrict__ Wt,
    u16* __restrict__ H, const float* __restrict__ invo,
    const float* __restrict__ a_soft, int aidx, int n) {
  __shared__ __align__(16) u16 xl[64 * 136];
  int tid = threadIdx.x;
  int row0 = blockIdx.x * 64;
#pragma unroll
  for (int j = 0; j < 8; ++j) {
    int idx = tid + 256 * j;
    int r = idx >> 5, c4 = (idx & 31) * 4;
    float4 v = make_float4(0.f, 0.f, 0.f, 0.f);
    if (row0 + r < n) v = *(const float4*)&X[(size_t)(row0 + r) * 128 + c4];
    ushort4 o;
    o.x = f2bf(v.x); o.y = f2bf(v.y); o.z = f2bf(v.z); o.w = f2bf(v.w);
    *(ushort4*)&xl[r * 136 + c4] = o;
  }
  __syncthreads();

  int lane = tid & 63, w = tid >> 6;
  int m15 = lane & 15, kg = lane >> 4;   // A row / B col select, k-group 0..3
  f32x4 acc[8];
#pragma unroll
  for (int i = 0; i < 8; ++i) acc[i] = (f32x4){0.f, 0.f, 0.f, 0.f};

  const u16* xrow = &xl[(w * 16 + m15) * 136 + kg * 8];
#pragma unroll
  for (int ks = 0; ks < 4; ++ks) {
    short8 a = *(const short8*)&xrow[ks * 32];
#pragma unroll
    for (int fn = 0; fn < 8; ++fn) {
      short8 b = *(const short8*)&Wt[(size_t)(fn * 16 + m15) * 128 + kg * 8 + ks * 32];
      acc[fn] = __builtin_amdgcn_mfma_f32_16x16x32_bf16(a, b, acc[fn], 0, 0, 0);
    }
  }

  float as = a_soft[aidx];
  int rbase = row0 + w * 16 + kg * 4;
  float sc[4];
#pragma unroll
  for (int r = 0; r < 4; ++r)
    sc[r] = (rbase + r < n) ? as * invo[rbase + r] : 0.f;
#pragma unroll
  for (int fn = 0; fn < 8; ++fn) {
#pragma unroll
    for (int r = 0; r < 4; ++r) {
      int rr = rbase + r;
      if (rr < n) H[(size_t)rr * 128 + fn * 16 + m15] = f2bf(acc[fn][r] * sc[r]);
    }
  }
}

// fused gather(bf16) + bias + relu + residual + l2norm; one wave per row.
__global__ __launch_bounds__(256) void aggfin_k(
    const float* __restrict__ Xt,
    const u16* __restrict__ H1, const u16* __restrict__ H2,
    const int* __restrict__ rs1, const int* __restrict__ es1,
    const int* __restrict__ rs2, const int* __restrict__ es2,
    const float* __restrict__ invi1, const float* __restrict__ invi2,
    const float* __restrict__ b1, const float* __restrict__ b2,
    const float* __restrict__ a_soft, int t,
    float* __restrict__ Xn, int n, int hop2) {
  int w = threadIdx.x >> 6, lane = threadIdx.x & 63;
  int row = blockIdx.x * 4 + w;
  if (row >= n) return;
  int half = lane >> 5;
  int cl = (lane & 31) * 4;

  float t0 = 0.f, t1 = 0.f, t2 = 0.f, t3 = 0.f;
  {
    float a0 = 0.f, a1 = 0.f, a2 = 0.f, a3 = 0.f;
    int e0 = rs1[row], e1 = rs1[row + 1];
    for (int e = e0 + half; e < e1; e += 2) {
      int s = es1[e];
      ushort4 h = *(const ushort4*)&H1[(size_t)s * 128 + cl];
      a0 += bf2f(h.x); a1 += bf2f(h.y); a2 += bf2f(h.z); a3 += bf2f(h.w);
    }
    float gi = invi1[row];
    t0 = a0 * gi; t1 = a1 * gi; t2 = a2 * gi; t3 = a3 * gi;
  }
  if (hop2) {
    float a0 = 0.f, a1 = 0.f, a2 = 0.f, a3 = 0.f;
    int e0 = rs2[row], e1 = rs2[row + 1];
    for (int e = e0 + half; e < e1; e += 2) {
      int s = es2[e];
      ushort4 h = *(const ushort4*)&H2[(size_t)s * 128 + cl];
      a0 += bf2f(h.x); a1 += bf2f(h.y); a2 += bf2f(h.z); a3 += bf2f(h.w);
    }
    float gi = invi2[row];
    t0 += a0 * gi; t1 += a1 * gi; t2 += a2 * gi; t3 += a3 * gi;
  }
  t0 += __shfl_xor(t0, 32, 64);
  t1 += __shfl_xor(t1, 32, 64);
  t2 += __shfl_xor(t2, 32, 64);
  t3 += __shfl_xor(t3, 32, 64);

  float a0s = a_soft[2 * t], a1s = a_soft[2 * t + 1];
  float4 bv1 = *(const float4*)&b1[cl];
  float4 bv2 = *(const float4*)&b2[cl];
  float4 x = *(const float4*)&Xt[(size_t)row * 128 + cl];
  float v0 = x.x + fmaxf(t0 + a0s * bv1.x + a1s * bv2.x, 0.f);
  float v1 = x.y + fmaxf(t1 + a0s * bv1.y + a1s * bv2.y, 0.f);
  float v2 = x.z + fmaxf(t2 + a0s * bv1.z + a1s * bv2.z, 0.f);
  float v3 = x.w + fmaxf(t3 + a0s * bv1.w + a1s * bv2.w, 0.f);
  float ss = v0 * v0 + v1 * v1 + v2 * v2 + v3 * v3;
#pragma unroll
  for (int off = 16; off >= 1; off >>= 1) ss += __shfl_xor(ss, off, 64);
  float inv = 1.0f / fmaxf(sqrtf(ss), 1e-12f);
  if (half == 0)
    *(float4*)&Xn[(size_t)row * 128 + cl] =
        make_float4(v0 * inv, v1 * inv, v2 * inv, v3 * inv);
}

extern "C" void kernel_launch(void* const* d_in, const int* in_sizes, int n_in,
                              void* d_out, int out_size, void* d_ws, size_t ws_size,
                              hipStream_t stream) {
  const float* x_in  = (const float*)d_in[0];
  const float* W1    = (const float*)d_in[1];
  const float* b1    = (const float*)d_in[2];
  const float* W2    = (const float*)d_in[3];
  const float* b2    = (const float*)d_in[4];
  const float* alpha = (const float*)d_in[5];
  const int* src1 = (const int*)d_in[6];
  const int* dst1 = (const int*)d_in[7];
  const int* src2 = (const int*)d_in[8];
  const int* dst2 = (const int*)d_in[9];

  int N = in_sizes[0] / 128;
  int Lnum = in_sizes[5] / 2;
  int E1 = in_sizes[6], E2 = in_sizes[8];

  size_t ND = (size_t)N * 128;
  float* xA = (float*)d_ws;
  float* xB = xA + ND;
  u16* h1 = (u16*)(xB + ND);
  u16* h2 = h1 + ND;
  float* degs = (float*)(h2 + ND);   // 4*N floats: invo1, invi1, invo2, invi2
  float* a_soft = degs + 4 * (size_t)N;
  int* ibase = (int*)(a_soft + 64);
  int* cnto1 = ibase;                // N   (order must match degs: o1,i1,o2,i2)
  int* cnti1 = cnto1 + N;            // N
  int* cnto2 = cnti1 + N;            // N
  int* cnti2 = cnto2 + N;            // N
  int* rs1   = cnti2 + N;            // N+1
  int* rs2   = rs1 + N + 1;          // N+1
  int* cur1  = rs2 + N + 1;          // N
  int* cur2  = cur1 + N;             // N
  int* bsum  = cur2 + N;             // 256
  int* boff  = bsum + 256;           // 256
  int* es1   = boff + 256;           // E1
  int* es2   = es1 + E1;             // E2
  u16* wt1 = (u16*)((((uintptr_t)(es2 + E2)) + 15) & ~(uintptr_t)15);
  u16* wt2 = wt1 + (size_t)Lnum * 16384;

  float* invo1 = degs;
  float* invi1 = degs + N;
  float* invo2 = degs + 2 * (size_t)N;
  float* invi2 = degs + 3 * (size_t)N;

  int nb = (N + 1023) / 1024;

  hipMemsetAsync(cnto1, 0, 4 * (size_t)N * sizeof(int), stream);
  softmax_k<<<1, 64, 0, stream>>>(alpha, a_soft, Lnum);
  prep_w_k<<<(2 * Lnum * 4096 + 255) / 256, 256, 0, stream>>>(W1, W2, wt1, wt2, Lnum);
  deg_k<<<(E1 + 255) / 256, 256, 0, stream>>>(src1, dst1, cnto1, cnti1, E1);
  deg_k<<<(E2 + 255) / 256, 256, 0, stream>>>(src2, dst2, cnto2, cnti2, E2);
  inv_k<<<(4 * N + 255) / 256, 256, 0, stream>>>(cnto1, degs, 4 * N);
  psum_k<<<nb, 256, 0, stream>>>(cnti1, bsum, N);
  bscan_k<<<1, 256, 0, stream>>>(bsum, boff, rs1, nb, N);
  sapply_k<<<nb, 256, 0, stream>>>(cnti1, boff, rs1, cur1, N);
  psum_k<<<nb, 256, 0, stream>>>(cnti2, bsum, N);
  bscan_k<<<1, 256, 0, stream>>>(bsum, boff, rs2, nb, N);
  sapply_k<<<nb, 256, 0, stream>>>(cnti2, boff, rs2, cur2, N);
  place_k<<<(E1 + 255) / 256, 256, 0, stream>>>(src1, dst1, cur1, es1, E1);
  place_k<<<(E2 + 255) / 256, 256, 0, stream>>>(src2, dst2, cur2, es2, E2);

  float* out = (float*)d_out;
  int gemm_grid = (N + 63) / 64;
  int fin_grid = (N + 3) / 4;

  const float* prev = nullptr;
  const float* cur = x_in;
  for (int t = 0; t < Lnum; ++t) {
    float* nxt = (t == Lnum - 1) ? out : ((t & 1) ? xB : xA);
    gemm_mfma_k<<<gemm_grid, 256, 0, stream>>>(cur, wt1 + (size_t)t * 16384, h1,
                                               invo1, a_soft, 2 * t, N);
    if (t > 0)
      gemm_mfma_k<<<gemm_grid, 256, 0, stream>>>(prev, wt2 + (size_t)t * 16384, h2,
                                                 invo2, a_soft, 2 * t + 1, N);
    aggfin_k<<<fin_grid, 256, 0, stream>>>(cur, h1, h2, rs1, es1, rs2, es2,
                                           invi1, invi2,
                                           b1 + (size_t)t * 128, b2 + (size_t)t * 128,
                                           a_soft, t, nxt, N, t > 0 ? 1 : 0);
    prev = cur;
    cur = nxt;
  }
}

// Round 6
// 421.053 us; speedup vs baseline: 4.9858x; 1.0850x over previous
//
#include <hip/hip_runtime.h>

// ---------------------------------------------------------------------------
// DelayGNN stage, CSR-gather + bf16-MFMA GEMM, bf16 node features end-to-end:
//   xb = bf16(x); per layer t:
//     H1 = bf16((xb_t @ W1[t]) * (a0*invo1[row]))     mfma_f32_16x16x32_bf16
//     H2 = bf16((xb_{t-1} @ W2[t]) * (a1*invo2[row])) (t>0)
//     row r: agg = invi1[r]*sum_CSR1 H1[src] + invi2[r]*sum_CSR2 H2[src]
//     x_{t+1}[r] = l2norm(x_t[r] + relu(agg + bb[t]))   bb = a0*b1 + a1*b2
//   last layer writes fp32 to d_out, others bf16 ping-pong.
// ---------------------------------------------------------------------------

typedef unsigned short u16;
typedef __attribute__((ext_vector_type(8))) short short8;    // 8 bf16
typedef __attribute__((ext_vector_type(8))) unsigned short ushort8;
typedef __attribute__((ext_vector_type(4))) float f32x4;

__device__ inline float bf2f(u16 u) {
  return __uint_as_float(((unsigned int)u) << 16);
}
__device__ inline u16 f2bf(float f) {  // RNE
  unsigned int u = __float_as_uint(f);
  return (u16)((u + 0x7fff + ((u >> 16) & 1)) >> 16);
}

__global__ __launch_bounds__(64) void softmax_k(const float* __restrict__ alpha,
                                                float* __restrict__ a_soft, int Lnum) {
  int t = threadIdx.x;
  if (t >= Lnum) return;
  if (t == 0) { a_soft[0] = 1.0f; a_soft[1] = 0.0f; return; }
  float x0 = alpha[2 * t], x1 = alpha[2 * t + 1];
  float m = fmaxf(x0, x1);
  float e0 = expf(x0 - m), e1 = expf(x1 - m);
  float inv = 1.0f / (e0 + e1);
  a_soft[2 * t] = e0 * inv;
  a_soft[2 * t + 1] = e1 * inv;
}

// fused bias: bb[t][c] = a0*b1[t][c] + a1*b2[t][c]
__global__ __launch_bounds__(256) void prep_bb_k(const float* __restrict__ b1,
                                                 const float* __restrict__ b2,
                                                 const float* __restrict__ a_soft,
                                                 float* __restrict__ bb, int Lnum) {
  int id = blockIdx.x * 256 + threadIdx.x;
  if (id >= Lnum * 128) return;
  int t = id >> 7;
  bb[id] = a_soft[2 * t] * b1[id] + a_soft[2 * t + 1] * b2[id];
}

// x fp32 -> bf16
__global__ __launch_bounds__(256) void xcvt_k(const float* __restrict__ X,
                                              u16* __restrict__ Xb, size_t n8) {
  size_t id = (size_t)blockIdx.x * 256 + threadIdx.x;
  if (id >= n8) return;
  const float4* p = (const float4*)(X + id * 8);
  float4 v0 = p[0], v1 = p[1];
  ushort8 o;
  o[0] = f2bf(v0.x); o[1] = f2bf(v0.y); o[2] = f2bf(v0.z); o[3] = f2bf(v0.w);
  o[4] = f2bf(v1.x); o[5] = f2bf(v1.y); o[6] = f2bf(v1.z); o[7] = f2bf(v1.w);
  *(ushort8*)(Xb + id * 8) = o;
}

// W [k][n] fp32 -> Wt [n][k] bf16, all 2*Lnum matrices
__global__ __launch_bounds__(256) void prep_w_k(const float* __restrict__ W1,
                                                const float* __restrict__ W2,
                                                u16* __restrict__ Wt1,
                                                u16* __restrict__ Wt2, int Lnum) {
  int id = blockIdx.x * 256 + threadIdx.x;
  int per = 128 * 32;
  int mat = id / per, rem = id - mat * per;
  if (mat >= 2 * Lnum) return;
  int k = rem >> 5, n4 = (rem & 31) * 4;
  const float* W = (mat < Lnum) ? (W1 + (size_t)mat * 16384)
                                : (W2 + (size_t)(mat - Lnum) * 16384);
  u16* Wt = (mat < Lnum) ? (Wt1 + (size_t)mat * 16384)
                         : (Wt2 + (size_t)(mat - Lnum) * 16384);
  float4 v = *(const float4*)&W[k * 128 + n4];
  Wt[(size_t)(n4 + 0) * 128 + k] = f2bf(v.x);
  Wt[(size_t)(n4 + 1) * 128 + k] = f2bf(v.y);
  Wt[(size_t)(n4 + 2) * 128 + k] = f2bf(v.z);
  Wt[(size_t)(n4 + 3) * 128 + k] = f2bf(v.w);
}

__global__ __launch_bounds__(256) void deg_k(const int* __restrict__ src,
                                             const int* __restrict__ dst,
                                             int* __restrict__ cnto,
                                             int* __restrict__ cnti, int E) {
  int i = threadIdx.x + blockIdx.x * 256;
  if (i >= E) return;
  atomicAdd(&cnto[src[i]], 1);
  atomicAdd(&cnti[dst[i]], 1);
}

__global__ __launch_bounds__(256) void inv_k(const int* __restrict__ cnt,
                                             float* __restrict__ inv, int n) {
  int i = threadIdx.x + blockIdx.x * 256;
  if (i >= n) return;
  int v = cnt[i];
  inv[i] = (v > 0) ? rsqrtf((float)v) : 0.0f;
}

__global__ __launch_bounds__(256) void psum_k(const int* __restrict__ cnt,
                                              int* __restrict__ bsums, int n) {
  int base = blockIdx.x * 1024 + threadIdx.x * 4;
  int s = 0;
#pragma unroll
  for (int j = 0; j < 4; ++j) { int i = base + j; if (i < n) s += cnt[i]; }
#pragma unroll
  for (int off = 1; off < 64; off <<= 1) s += __shfl_xor(s, off, 64);
  __shared__ int ws[4];
  int lane = threadIdx.x & 63, w = threadIdx.x >> 6;
  if (lane == 0) ws[w] = s;
  __syncthreads();
  if (threadIdx.x == 0) bsums[blockIdx.x] = ws[0] + ws[1] + ws[2] + ws[3];
}

__global__ __launch_bounds__(256) void bscan_k(const int* __restrict__ bsums,
                                               int* __restrict__ boffs,
                                               int* __restrict__ row_start,
                                               int nb, int n) {
  __shared__ int sm[256];
  int tid = threadIdx.x;
  int v = (tid < nb) ? bsums[tid] : 0;
  sm[tid] = v;
  __syncthreads();
  for (int off = 1; off < 256; off <<= 1) {
    int u = (tid >= off) ? sm[tid - off] : 0;
    __syncthreads();
    sm[tid] += u;
    __syncthreads();
  }
  if (tid < nb) boffs[tid] = sm[tid] - v;
  if (tid == 255) row_start[n] = sm[255];
}

__global__ __launch_bounds__(256) void sapply_k(const int* __restrict__ cnt,
                                                const int* __restrict__ boffs,
                                                int* __restrict__ row_start,
                                                int* __restrict__ cursor, int n) {
  int lane = threadIdx.x & 63, w = threadIdx.x >> 6;
  int base = blockIdx.x * 1024 + threadIdx.x * 4;
  int c[4], s = 0;
#pragma unroll
  for (int j = 0; j < 4; ++j) { int i = base + j; c[j] = (i < n) ? cnt[i] : 0; s += c[j]; }
  int incl = s;
#pragma unroll
  for (int off = 1; off < 64; off <<= 1) {
    int u = __shfl_up(incl, off, 64);
    if (lane >= off) incl += u;
  }
  int excl = incl - s;
  __shared__ int ws[4];
  if (lane == 63) ws[w] = incl;
  __syncthreads();
  int woff = 0;
  for (int i = 0; i < w; ++i) woff += ws[i];
  int off0 = boffs[blockIdx.x] + woff + excl;
#pragma unroll
  for (int j = 0; j < 4; ++j) {
    int i = base + j;
    if (i < n) { row_start[i] = off0; cursor[i] = off0; off0 += c[j]; }
  }
}

__global__ __launch_bounds__(256) void place_k(const int* __restrict__ src,
                                               const int* __restrict__ dst,
                                               int* __restrict__ cursor,
                                               int* __restrict__ esrc, int E) {
  int i = threadIdx.x + blockIdx.x * 256;
  if (i >= E) return;
  int slot = atomicAdd(&cursor[dst[i]], 1);
  esrc[slot] = src[i];
}

// H[r][c] = bf16((Xb[r][:] @ W[:,c]) * (a_soft[aidx]*invo[r])).
// No LDS: each X element is consumed by exactly one lane -> direct short8
// global loads (wave reads 16 consecutive 256B rows, coalesced).
// Block 256 = 4 waves x 16 rows; 8 col-frags x 4 k-steps of 16x16x32 MFMA.
__global__ __launch_bounds__(256) void gemm_mfma_k(
    const u16* __restrict__ Xb, const u16* __restrict__ Wt,
    u16* __restrict__ H, const float* __restrict__ invo,
    const float* __restrict__ a_soft, int aidx, int n) {
  int tid = threadIdx.x;
  int lane = tid & 63, w = tid >> 6;
  int m15 = lane & 15, kg = lane >> 4;
  int row0 = blockIdx.x * 64;
  int arow = row0 + w * 16 + m15;
  int rc = (arow < n) ? arow : (n - 1);
  const u16* xrow = &Xb[(size_t)rc * 128 + kg * 8];

  f32x4 acc[8];
#pragma unroll
  for (int i = 0; i < 8; ++i) acc[i] = (f32x4){0.f, 0.f, 0.f, 0.f};

#pragma unroll
  for (int ks = 0; ks < 4; ++ks) {
    short8 a = *(const short8*)&xrow[ks * 32];
#pragma unroll
    for (int fn = 0; fn < 8; ++fn) {
      short8 b = *(const short8*)&Wt[(size_t)(fn * 16 + m15) * 128 + kg * 8 + ks * 32];
      acc[fn] = __builtin_amdgcn_mfma_f32_16x16x32_bf16(a, b, acc[fn], 0, 0, 0);
    }
  }

  float as = a_soft[aidx];
  int rbase = row0 + w * 16 + kg * 4;
  float sc[4];
#pragma unroll
  for (int r = 0; r < 4; ++r)
    sc[r] = (rbase + r < n) ? as * invo[rbase + r] : 0.f;
#pragma unroll
  for (int fn = 0; fn < 8; ++fn) {
#pragma unroll
    for (int r = 0; r < 4; ++r) {
      int rr = rbase + r;
      if (rr < n) H[(size_t)rr * 128 + fn * 16 + m15] = f2bf(acc[fn][r] * sc[r]);
    }
  }
}

// fused gather + bias + relu + residual + l2norm; one wave per row.
// 16-lane groups: lane covers 8 cols (16B); group g handles edges e==g (mod 4)
// -> 4 edge rows in flight per wave; combine via shfl_xor(16,32).
__global__ __launch_bounds__(256) void aggfin_k(
    const u16* __restrict__ Xb,
    const u16* __restrict__ H1, const u16* __restrict__ H2,
    const int* __restrict__ rs1, const int* __restrict__ es1,
    const int* __restrict__ rs2, const int* __restrict__ es2,
    const float* __restrict__ invi1, const float* __restrict__ invi2,
    const float* __restrict__ bb,
    u16* __restrict__ XnB, float* __restrict__ XnF,
    int n, int hop2, int final_f32) {
  int w = threadIdx.x >> 6, lane = threadIdx.x & 63;
  int row = blockIdx.x * 4 + w;
  if (row >= n) return;
  int grp = lane >> 4, l16 = lane & 15;
  int c8 = l16 * 8;

  float t[8];
#pragma unroll
  for (int j = 0; j < 8; ++j) t[j] = 0.f;
  {
    float a[8];
#pragma unroll
    for (int j = 0; j < 8; ++j) a[j] = 0.f;
    int e0 = rs1[row], e1 = rs1[row + 1];
    for (int e = e0 + grp; e < e1; e += 4) {
      int s = es1[e];
      ushort8 h = *(const ushort8*)&H1[(size_t)s * 128 + c8];
#pragma unroll
      for (int j = 0; j < 8; ++j) a[j] += bf2f(h[j]);
    }
    float gi = invi1[row];
#pragma unroll
    for (int j = 0; j < 8; ++j) t[j] = a[j] * gi;
  }
  if (hop2) {
    float a[8];
#pragma unroll
    for (int j = 0; j < 8; ++j) a[j] = 0.f;
    int e0 = rs2[row], e1 = rs2[row + 1];
    for (int e = e0 + grp; e < e1; e += 4) {
      int s = es2[e];
      ushort8 h = *(const ushort8*)&H2[(size_t)s * 128 + c8];
#pragma unroll
      for (int j = 0; j < 8; ++j) a[j] += bf2f(h[j]);
    }
    float gi = invi2[row];
#pragma unroll
    for (int j = 0; j < 8; ++j) t[j] += a[j] * gi;
  }
#pragma unroll
  for (int j = 0; j < 8; ++j) t[j] += __shfl_xor(t[j], 16, 64);
#pragma unroll
  for (int j = 0; j < 8; ++j) t[j] += __shfl_xor(t[j], 32, 64);

  float4 bv0 = *(const float4*)&bb[c8];
  float4 bv1 = *(const float4*)&bb[c8 + 4];
  float bbv[8] = {bv0.x, bv0.y, bv0.z, bv0.w, bv1.x, bv1.y, bv1.z, bv1.w};
  ushort8 xv = *(const ushort8*)&Xb[(size_t)row * 128 + c8];
  float v[8];
  float ss = 0.f;
#pragma unroll
  for (int j = 0; j < 8; ++j) {
    v[j] = bf2f(xv[j]) + fmaxf(t[j] + bbv[j], 0.f);
    ss += v[j] * v[j];
  }
#pragma unroll
  for (int off = 1; off <= 8; off <<= 1) ss += __shfl_xor(ss, off, 64);
  float inv = 1.0f / fmaxf(sqrtf(ss), 1e-12f);

  if (final_f32) {
    if (grp == 0) {
      float4 o0 = make_float4(v[0] * inv, v[1] * inv, v[2] * inv, v[3] * inv);
      float4 o1 = make_float4(v[4] * inv, v[5] * inv, v[6] * inv, v[7] * inv);
      *(float4*)&XnF[(size_t)row * 128 + c8] = o0;
      *(float4*)&XnF[(size_t)row * 128 + c8 + 4] = o1;
    }
  } else {
    if (grp == 0) {
      ushort8 o;
#pragma unroll
      for (int j = 0; j < 8; ++j) o[j] = f2bf(v[j] * inv);
      *(ushort8*)&XnB[(size_t)row * 128 + c8] = o;
    }
  }
}

extern "C" void kernel_launch(void* const* d_in, const int* in_sizes, int n_in,
                              void* d_out, int out_size, void* d_ws, size_t ws_size,
                              hipStream_t stream) {
  const float* x_in  = (const float*)d_in[0];
  const float* W1    = (const float*)d_in[1];
  const float* b1    = (const float*)d_in[2];
  const float* W2    = (const float*)d_in[3];
  const float* b2    = (const float*)d_in[4];
  const float* alpha = (const float*)d_in[5];
  const int* src1 = (const int*)d_in[6];
  const int* dst1 = (const int*)d_in[7];
  const int* src2 = (const int*)d_in[8];
  const int* dst2 = (const int*)d_in[9];

  int N = in_sizes[0] / 128;
  int Lnum = in_sizes[5] / 2;
  int E1 = in_sizes[6], E2 = in_sizes[8];

  size_t ND = (size_t)N * 128;
  u16* xb0 = (u16*)d_ws;             // 3 bf16 x buffers (x3 reuses xb0)
  u16* xbA = xb0 + ND;
  u16* xbB = xbA + ND;
  u16* h1  = xbB + ND;
  u16* h2  = h1 + ND;
  float* degs = (float*)(h2 + ND);   // 4*N floats: invo1, invi1, invo2, invi2
  float* a_soft = degs + 4 * (size_t)N;
  float* bb = a_soft + 64;           // Lnum*128
  int* ibase = (int*)(bb + 512);
  int* cnto1 = ibase;                // order must match degs: o1,i1,o2,i2
  int* cnti1 = cnto1 + N;
  int* cnto2 = cnti1 + N;
  int* cnti2 = cnto2 + N;
  int* rs1   = cnti2 + N;            // N+1
  int* rs2   = rs1 + N + 1;          // N+1
  int* cur1  = rs2 + N + 1;          // N
  int* cur2  = cur1 + N;             // N
  int* bsum  = cur2 + N;             // 256
  int* boff  = bsum + 256;           // 256
  int* es1   = boff + 256;           // E1
  int* es2   = es1 + E1;             // E2
  u16* wt1 = (u16*)((((uintptr_t)(es2 + E2)) + 15) & ~(uintptr_t)15);
  u16* wt2 = wt1 + (size_t)Lnum * 16384;

  float* invo1 = degs;
  float* invi1 = degs + N;
  float* invo2 = degs + 2 * (size_t)N;
  float* invi2 = degs + 3 * (size_t)N;

  int nb = (N + 1023) / 1024;

  hipMemsetAsync(cnto1, 0, 4 * (size_t)N * sizeof(int), stream);
  softmax_k<<<1, 64, 0, stream>>>(alpha, a_soft, Lnum);
  prep_bb_k<<<(Lnum * 128 + 255) / 256, 256, 0, stream>>>(b1, b2, a_soft, bb, Lnum);
  prep_w_k<<<(2 * Lnum * 4096 + 255) / 256, 256, 0, stream>>>(W1, W2, wt1, wt2, Lnum);
  xcvt_k<<<(int)((ND / 8 + 255) / 256), 256, 0, stream>>>(x_in, xb0, ND / 8);
  deg_k<<<(E1 + 255) / 256, 256, 0, stream>>>(src1, dst1, cnto1, cnti1, E1);
  deg_k<<<(E2 + 255) / 256, 256, 0, stream>>>(src2, dst2, cnto2, cnti2, E2);
  inv_k<<<(4 * N + 255) / 256, 256, 0, stream>>>(cnto1, degs, 4 * N);
  psum_k<<<nb, 256, 0, stream>>>(cnti1, bsum, N);
  bscan_k<<<1, 256, 0, stream>>>(bsum, boff, rs1, nb, N);
  sapply_k<<<nb, 256, 0, stream>>>(cnti1, boff, rs1, cur1, N);
  psum_k<<<nb, 256, 0, stream>>>(cnti2, bsum, N);
  bscan_k<<<1, 256, 0, stream>>>(bsum, boff, rs2, nb, N);
  sapply_k<<<nb, 256, 0, stream>>>(cnti2, boff, rs2, cur2, N);
  place_k<<<(E1 + 255) / 256, 256, 0, stream>>>(src1, dst1, cur1, es1, E1);
  place_k<<<(E2 + 255) / 256, 256, 0, stream>>>(src2, dst2, cur2, es2, E2);

  float* out = (float*)d_out;
  int gemm_grid = (N + 63) / 64;
  int fin_grid = (N + 3) / 4;

  // x buffers per layer: x0=xb0, x1=xbA, x2=xbB, x3=xb0 (x0 dead after t=1)
  u16* xbuf[8];
  xbuf[0] = xb0; xbuf[1] = xbA; xbuf[2] = xbB;
  for (int i = 3; i < 8; ++i) xbuf[i] = xbuf[i - 3];

  for (int t = 0; t < Lnum; ++t) {
    const u16* cur = xbuf[t];
    const u16* prev = (t > 0) ? xbuf[t - 1] : nullptr;
    int fin = (t == Lnum - 1);
    u16* nxt = fin ? nullptr : xbuf[t + 1];
    gemm_mfma_k<<<gemm_grid, 256, 0, stream>>>(cur, wt1 + (size_t)t * 16384, h1,
                                               invo1, a_soft, 2 * t, N);
    if (t > 0)
      gemm_mfma_k<<<gemm_grid, 256, 0, stream>>>(prev, wt2 + (size_t)t * 16384, h2,
                                                 invo2, a_soft, 2 * t + 1, N);
    aggfin_k<<<fin_grid, 256, 0, stream>>>(cur, h1, h2, rs1, es1, rs2, es2,
                                           invi1, invi2, bb + (size_t)t * 128,
                                           nxt, out, N, t > 0 ? 1 : 0, fin);
  }
}

// Round 7
// 330.869 us; speedup vs baseline: 6.3448x; 1.2726x over previous
//
#include <hip/hip_runtime.h>

// ---------------------------------------------------------------------------
// DelayGNN stage, CSR-gather + bf16-MFMA GEMM (W staged in LDS, XOR-swizzled),
// bf16 node features end-to-end:
//   xb = bf16(x); per layer t:
//     H1 = bf16((xb_t @ W1[t]) * (a0*invo1[row]))     mfma_f32_16x16x32_bf16
//     H2 = bf16((xb_{t-1} @ W2[t]) * (a1*invo2[row])) (t>0)
//     row r: agg = invi1[r]*sum_CSR1 H1[src] + invi2[r]*sum_CSR2 H2[src]
//     x_{t+1}[r] = l2norm(x_t[r] + relu(agg + bb[t]))   bb = a0*b1 + a1*b2
//   last layer writes fp32 to d_out, others bf16 ping-pong.
// ---------------------------------------------------------------------------

typedef unsigned short u16;
typedef __attribute__((ext_vector_type(8))) short short8;    // 8 bf16
typedef __attribute__((ext_vector_type(8))) unsigned short ushort8;
typedef __attribute__((ext_vector_type(4))) float f32x4;

__device__ inline float bf2f(u16 u) {
  return __uint_as_float(((unsigned int)u) << 16);
}
__device__ inline u16 f2bf(float f) {  // RNE
  unsigned int u = __float_as_uint(f);
  return (u16)((u + 0x7fff + ((u >> 16) & 1)) >> 16);
}

__global__ __launch_bounds__(64) void softmax_k(const float* __restrict__ alpha,
                                                float* __restrict__ a_soft, int Lnum) {
  int t = threadIdx.x;
  if (t >= Lnum) return;
  if (t == 0) { a_soft[0] = 1.0f; a_soft[1] = 0.0f; return; }
  float x0 = alpha[2 * t], x1 = alpha[2 * t + 1];
  float m = fmaxf(x0, x1);
  float e0 = expf(x0 - m), e1 = expf(x1 - m);
  float inv = 1.0f / (e0 + e1);
  a_soft[2 * t] = e0 * inv;
  a_soft[2 * t + 1] = e1 * inv;
}

// fused bias: bb[t][c] = a0*b1[t][c] + a1*b2[t][c]
__global__ __launch_bounds__(256) void prep_bb_k(const float* __restrict__ b1,
                                                 const float* __restrict__ b2,
                                                 const float* __restrict__ a_soft,
                                                 float* __restrict__ bb, int Lnum) {
  int id = blockIdx.x * 256 + threadIdx.x;
  if (id >= Lnum * 128) return;
  int t = id >> 7;
  bb[id] = a_soft[2 * t] * b1[id] + a_soft[2 * t + 1] * b2[id];
}

// x fp32 -> bf16
__global__ __launch_bounds__(256) void xcvt_k(const float* __restrict__ X,
                                              u16* __restrict__ Xb, size_t n8) {
  size_t id = (size_t)blockIdx.x * 256 + threadIdx.x;
  if (id >= n8) return;
  const float4* p = (const float4*)(X + id * 8);
  float4 v0 = p[0], v1 = p[1];
  ushort8 o;
  o[0] = f2bf(v0.x); o[1] = f2bf(v0.y); o[2] = f2bf(v0.z); o[3] = f2bf(v0.w);
  o[4] = f2bf(v1.x); o[5] = f2bf(v1.y); o[6] = f2bf(v1.z); o[7] = f2bf(v1.w);
  *(ushort8*)(Xb + id * 8) = o;
}

// W [k][n] fp32 -> Wt [n][k] bf16, all 2*Lnum matrices
__global__ __launch_bounds__(256) void prep_w_k(const float* __restrict__ W1,
                                                const float* __restrict__ W2,
                                                u16* __restrict__ Wt1,
                                                u16* __restrict__ Wt2, int Lnum) {
  int id = blockIdx.x * 256 + threadIdx.x;
  int per = 128 * 32;
  int mat = id / per, rem = id - mat * per;
  if (mat >= 2 * Lnum) return;
  int k = rem >> 5, n4 = (rem & 31) * 4;
  const float* W = (mat < Lnum) ? (W1 + (size_t)mat * 16384)
                                : (W2 + (size_t)(mat - Lnum) * 16384);
  u16* Wt = (mat < Lnum) ? (Wt1 + (size_t)mat * 16384)
                         : (Wt2 + (size_t)(mat - Lnum) * 16384);
  float4 v = *(const float4*)&W[k * 128 + n4];
  Wt[(size_t)(n4 + 0) * 128 + k] = f2bf(v.x);
  Wt[(size_t)(n4 + 1) * 128 + k] = f2bf(v.y);
  Wt[(size_t)(n4 + 2) * 128 + k] = f2bf(v.z);
  Wt[(size_t)(n4 + 3) * 128 + k] = f2bf(v.w);
}

__global__ __launch_bounds__(256) void deg_k(const int* __restrict__ src,
                                             const int* __restrict__ dst,
                                             int* __restrict__ cnto,
                                             int* __restrict__ cnti, int E) {
  int i = threadIdx.x + blockIdx.x * 256;
  if (i >= E) return;
  atomicAdd(&cnto[src[i]], 1);
  atomicAdd(&cnti[dst[i]], 1);
}

__global__ __launch_bounds__(256) void inv_k(const int* __restrict__ cnt,
                                             float* __restrict__ inv, int n) {
  int i = threadIdx.x + blockIdx.x * 256;
  if (i >= n) return;
  int v = cnt[i];
  inv[i] = (v > 0) ? rsqrtf((float)v) : 0.0f;
}

__global__ __launch_bounds__(256) void psum_k(const int* __restrict__ cnt,
                                              int* __restrict__ bsums, int n) {
  int base = blockIdx.x * 1024 + threadIdx.x * 4;
  int s = 0;
#pragma unroll
  for (int j = 0; j < 4; ++j) { int i = base + j; if (i < n) s += cnt[i]; }
#pragma unroll
  for (int off = 1; off < 64; off <<= 1) s += __shfl_xor(s, off, 64);
  __shared__ int ws[4];
  int lane = threadIdx.x & 63, w = threadIdx.x >> 6;
  if (lane == 0) ws[w] = s;
  __syncthreads();
  if (threadIdx.x == 0) bsums[blockIdx.x] = ws[0] + ws[1] + ws[2] + ws[3];
}

__global__ __launch_bounds__(256) void bscan_k(const int* __restrict__ bsums,
                                               int* __restrict__ boffs,
                                               int* __restrict__ row_start,
                                               int nb, int n) {
  __shared__ int sm[256];
  int tid = threadIdx.x;
  int v = (tid < nb) ? bsums[tid] : 0;
  sm[tid] = v;
  __syncthreads();
  for (int off = 1; off < 256; off <<= 1) {
    int u = (tid >= off) ? sm[tid - off] : 0;
    __syncthreads();
    sm[tid] += u;
    __syncthreads();
  }
  if (tid < nb) boffs[tid] = sm[tid] - v;
  if (tid == 255) row_start[n] = sm[255];
}

__global__ __launch_bounds__(256) void sapply_k(const int* __restrict__ cnt,
                                                const int* __restrict__ boffs,
                                                int* __restrict__ row_start,
                                                int* __restrict__ cursor, int n) {
  int lane = threadIdx.x & 63, w = threadIdx.x >> 6;
  int base = blockIdx.x * 1024 + threadIdx.x * 4;
  int c[4], s = 0;
#pragma unroll
  for (int j = 0; j < 4; ++j) { int i = base + j; c[j] = (i < n) ? cnt[i] : 0; s += c[j]; }
  int incl = s;
#pragma unroll
  for (int off = 1; off < 64; off <<= 1) {
    int u = __shfl_up(incl, off, 64);
    if (lane >= off) incl += u;
  }
  int excl = incl - s;
  __shared__ int ws[4];
  if (lane == 63) ws[w] = incl;
  __syncthreads();
  int woff = 0;
  for (int i = 0; i < w; ++i) woff += ws[i];
  int off0 = boffs[blockIdx.x] + woff + excl;
#pragma unroll
  for (int j = 0; j < 4; ++j) {
    int i = base + j;
    if (i < n) { row_start[i] = off0; cursor[i] = off0; off0 += c[j]; }
  }
}

__global__ __launch_bounds__(256) void place_k(const int* __restrict__ src,
                                               const int* __restrict__ dst,
                                               int* __restrict__ cursor,
                                               int* __restrict__ esrc, int E) {
  int i = threadIdx.x + blockIdx.x * 256;
  if (i >= E) return;
  int slot = atomicAdd(&cursor[dst[i]], 1);
  esrc[slot] = src[i];
}

// H[r][c] = bf16((Xb[r][:] @ W[:,c]) * (a_soft[aidx]*invo[r])).
// W (32KB bf16, [n][k]) staged in LDS with XOR swizzle (byte ^= (row&7)<<4)
// so the 16-row-strided ds_read_b128 B-frag reads are bank-conflict-free.
// Block 256 = 4 waves x 16 rows; 8 col-frags x 4 k-steps of 16x16x32 MFMA.
__global__ __launch_bounds__(256) void gemm_mfma_k(
    const u16* __restrict__ Xb, const u16* __restrict__ Wt,
    u16* __restrict__ H, const float* __restrict__ invo,
    const float* __restrict__ a_soft, int aidx, int n) {
  __shared__ __align__(16) u16 wl[128 * 128];
  int tid = threadIdx.x;
#pragma unroll
  for (int j = 0; j < 8; ++j) {            // stage 2048 x 16B of W
    int c = tid + 256 * j;
    int row = c >> 4, col8 = (c & 15) * 8;
    ushort8 v = *(const ushort8*)&Wt[(size_t)row * 128 + col8];
    *(ushort8*)&wl[row * 128 + (col8 ^ ((row & 7) * 8))] = v;
  }
  __syncthreads();

  int lane = tid & 63, w = tid >> 6;
  int m15 = lane & 15, kg = lane >> 4;
  int row0 = blockIdx.x * 64;
  int arow = row0 + w * 16 + m15;
  int rc = (arow < n) ? arow : (n - 1);
  const u16* xrow = &Xb[(size_t)rc * 128 + kg * 8];

  f32x4 acc[8];
#pragma unroll
  for (int i = 0; i < 8; ++i) acc[i] = (f32x4){0.f, 0.f, 0.f, 0.f};

#pragma unroll
  for (int ks = 0; ks < 4; ++ks) {
    short8 a = *(const short8*)&xrow[ks * 32];
#pragma unroll
    for (int fn = 0; fn < 8; ++fn) {
      int brow = fn * 16 + m15;
      int bcol = (kg * 8 + ks * 32) ^ ((m15 & 7) * 8);
      short8 b = *(const short8*)&wl[brow * 128 + bcol];
      acc[fn] = __builtin_amdgcn_mfma_f32_16x16x32_bf16(a, b, acc[fn], 0, 0, 0);
    }
  }

  float as = a_soft[aidx];
  int rbase = row0 + w * 16 + kg * 4;
  float sc[4];
#pragma unroll
  for (int r = 0; r < 4; ++r)
    sc[r] = (rbase + r < n) ? as * invo[rbase + r] : 0.f;
#pragma unroll
  for (int fn = 0; fn < 8; ++fn) {
#pragma unroll
    for (int r = 0; r < 4; ++r) {
      int rr = rbase + r;
      if (rr < n) H[(size_t)rr * 128 + fn * 16 + m15] = f2bf(acc[fn][r] * sc[r]);
    }
  }
}

// unpack 8 bf16 (uint4) and accumulate into 4 float2 (pairs -> v_pk_add_f32)
__device__ inline void upk_acc(float2* a, uint4 h) {
  a[0] = a[0] + make_float2(__uint_as_float(h.x << 16),
                            __uint_as_float(h.x & 0xffff0000u));
  a[1] = a[1] + make_float2(__uint_as_float(h.y << 16),
                            __uint_as_float(h.y & 0xffff0000u));
  a[2] = a[2] + make_float2(__uint_as_float(h.z << 16),
                            __uint_as_float(h.z & 0xffff0000u));
  a[3] = a[3] + make_float2(__uint_as_float(h.w << 16),
                            __uint_as_float(h.w & 0xffff0000u));
}

// fused gather + bias + relu + residual + l2norm; one wave per row.
// 16-lane groups: lane covers 8 cols (16B); group g handles edges e==g (mod 4);
// edge loop unrolled x2 (2 H rows + next indices in flight per group).
__global__ __launch_bounds__(256) void aggfin_k(
    const u16* __restrict__ Xb,
    const u16* __restrict__ H1, const u16* __restrict__ H2,
    const int* __restrict__ rs1, const int* __restrict__ es1,
    const int* __restrict__ rs2, const int* __restrict__ es2,
    const float* __restrict__ invi1, const float* __restrict__ invi2,
    const float* __restrict__ bb,
    u16* __restrict__ XnB, float* __restrict__ XnF,
    int n, int hop2, int final_f32) {
  int w = threadIdx.x >> 6, lane = threadIdx.x & 63;
  int row = blockIdx.x * 4 + w;
  if (row >= n) return;
  int grp = lane >> 4, l16 = lane & 15;
  int c8 = l16 * 8;

  float t[8];
  {
    float2 a[4] = {{0.f, 0.f}, {0.f, 0.f}, {0.f, 0.f}, {0.f, 0.f}};
    int e = rs1[row] + grp, e1 = rs1[row + 1];
    while (e + 4 < e1) {
      int s0 = es1[e], s1 = es1[e + 4];
      uint4 h0 = *(const uint4*)&H1[(size_t)s0 * 128 + c8];
      uint4 h1 = *(const uint4*)&H1[(size_t)s1 * 128 + c8];
      upk_acc(a, h0);
      upk_acc(a, h1);
      e += 8;
    }
    if (e < e1) {
      uint4 h = *(const uint4*)&H1[(size_t)es1[e] * 128 + c8];
      upk_acc(a, h);
    }
    float gi = invi1[row];
    t[0] = a[0].x * gi; t[1] = a[0].y * gi;
    t[2] = a[1].x * gi; t[3] = a[1].y * gi;
    t[4] = a[2].x * gi; t[5] = a[2].y * gi;
    t[6] = a[3].x * gi; t[7] = a[3].y * gi;
  }
  if (hop2) {
    float2 a[4] = {{0.f, 0.f}, {0.f, 0.f}, {0.f, 0.f}, {0.f, 0.f}};
    int e = rs2[row] + grp, e1 = rs2[row + 1];
    while (e + 4 < e1) {
      int s0 = es2[e], s1 = es2[e + 4];
      uint4 h0 = *(const uint4*)&H2[(size_t)s0 * 128 + c8];
      uint4 h1 = *(const uint4*)&H2[(size_t)s1 * 128 + c8];
      upk_acc(a, h0);
      upk_acc(a, h1);
      e += 8;
    }
    if (e < e1) {
      uint4 h = *(const uint4*)&H2[(size_t)es2[e] * 128 + c8];
      upk_acc(a, h);
    }
    float gi = invi2[row];
    t[0] += a[0].x * gi; t[1] += a[0].y * gi;
    t[2] += a[1].x * gi; t[3] += a[1].y * gi;
    t[4] += a[2].x * gi; t[5] += a[2].y * gi;
    t[6] += a[3].x * gi; t[7] += a[3].y * gi;
  }
#pragma unroll
  for (int j = 0; j < 8; ++j) t[j] += __shfl_xor(t[j], 16, 64);
#pragma unroll
  for (int j = 0; j < 8; ++j) t[j] += __shfl_xor(t[j], 32, 64);

  float4 bv0 = *(const float4*)&bb[c8];
  float4 bv1 = *(const float4*)&bb[c8 + 4];
  float bbv[8] = {bv0.x, bv0.y, bv0.z, bv0.w, bv1.x, bv1.y, bv1.z, bv1.w};
  ushort8 xv = *(const ushort8*)&Xb[(size_t)row * 128 + c8];
  float v[8];
  float ss = 0.f;
#pragma unroll
  for (int j = 0; j < 8; ++j) {
    v[j] = bf2f(xv[j]) + fmaxf(t[j] + bbv[j], 0.f);
    ss += v[j] * v[j];
  }
#pragma unroll
  for (int off = 1; off <= 8; off <<= 1) ss += __shfl_xor(ss, off, 64);
  float inv = 1.0f / fmaxf(sqrtf(ss), 1e-12f);

  if (final_f32) {
    if (grp == 0) {
      float4 o0 = make_float4(v[0] * inv, v[1] * inv, v[2] * inv, v[3] * inv);
      float4 o1 = make_float4(v[4] * inv, v[5] * inv, v[6] * inv, v[7] * inv);
      *(float4*)&XnF[(size_t)row * 128 + c8] = o0;
      *(float4*)&XnF[(size_t)row * 128 + c8 + 4] = o1;
    }
  } else {
    if (grp == 0) {
      ushort8 o;
#pragma unroll
      for (int j = 0; j < 8; ++j) o[j] = f2bf(v[j] * inv);
      *(ushort8*)&XnB[(size_t)row * 128 + c8] = o;
    }
  }
}

extern "C" void kernel_launch(void* const* d_in, const int* in_sizes, int n_in,
                              void* d_out, int out_size, void* d_ws, size_t ws_size,
                              hipStream_t stream) {
  const float* x_in  = (const float*)d_in[0];
  const float* W1    = (const float*)d_in[1];
  const float* b1    = (const float*)d_in[2];
  const float* W2    = (const float*)d_in[3];
  const float* b2    = (const float*)d_in[4];
  const float* alpha = (const float*)d_in[5];
  const int* src1 = (const int*)d_in[6];
  const int* dst1 = (const int*)d_in[7];
  const int* src2 = (const int*)d_in[8];
  const int* dst2 = (const int*)d_in[9];

  int N = in_sizes[0] / 128;
  int Lnum = in_sizes[5] / 2;
  int E1 = in_sizes[6], E2 = in_sizes[8];

  size_t ND = (size_t)N * 128;
  u16* xb0 = (u16*)d_ws;             // 3 bf16 x buffers (x3 reuses xb0)
  u16* xbA = xb0 + ND;
  u16* xbB = xbA + ND;
  u16* h1  = xbB + ND;
  u16* h2  = h1 + ND;
  float* degs = (float*)(h2 + ND);   // 4*N floats: invo1, invi1, invo2, invi2
  float* a_soft = degs + 4 * (size_t)N;
  float* bb = a_soft + 64;           // Lnum*128
  int* ibase = (int*)(bb + 512);
  int* cnto1 = ibase;                // order must match degs: o1,i1,o2,i2
  int* cnti1 = cnto1 + N;
  int* cnto2 = cnti1 + N;
  int* cnti2 = cnto2 + N;
  int* rs1   = cnti2 + N;            // N+1
  int* rs2   = rs1 + N + 1;          // N+1
  int* cur1  = rs2 + N + 1;          // N
  int* cur2  = cur1 + N;             // N
  int* bsum  = cur2 + N;             // 256
  int* boff  = bsum + 256;           // 256
  int* es1   = boff + 256;           // E1
  int* es2   = es1 + E1;             // E2
  u16* wt1 = (u16*)((((uintptr_t)(es2 + E2)) + 15) & ~(uintptr_t)15);
  u16* wt2 = wt1 + (size_t)Lnum * 16384;

  float* invo1 = degs;
  float* invi1 = degs + N;
  float* invo2 = degs + 2 * (size_t)N;
  float* invi2 = degs + 3 * (size_t)N;

  int nb = (N + 1023) / 1024;

  hipMemsetAsync(cnto1, 0, 4 * (size_t)N * sizeof(int), stream);
  softmax_k<<<1, 64, 0, stream>>>(alpha, a_soft, Lnum);
  prep_bb_k<<<(Lnum * 128 + 255) / 256, 256, 0, stream>>>(b1, b2, a_soft, bb, Lnum);
  prep_w_k<<<(2 * Lnum * 4096 + 255) / 256, 256, 0, stream>>>(W1, W2, wt1, wt2, Lnum);
  xcvt_k<<<(int)((ND / 8 + 255) / 256), 256, 0, stream>>>(x_in, xb0, ND / 8);
  deg_k<<<(E1 + 255) / 256, 256, 0, stream>>>(src1, dst1, cnto1, cnti1, E1);
  deg_k<<<(E2 + 255) / 256, 256, 0, stream>>>(src2, dst2, cnto2, cnti2, E2);
  inv_k<<<(4 * N + 255) / 256, 256, 0, stream>>>(cnto1, degs, 4 * N);
  psum_k<<<nb, 256, 0, stream>>>(cnti1, bsum, N);
  bscan_k<<<1, 256, 0, stream>>>(bsum, boff, rs1, nb, N);
  sapply_k<<<nb, 256, 0, stream>>>(cnti1, boff, rs1, cur1, N);
  psum_k<<<nb, 256, 0, stream>>>(cnti2, bsum, N);
  bscan_k<<<1, 256, 0, stream>>>(bsum, boff, rs2, nb, N);
  sapply_k<<<nb, 256, 0, stream>>>(cnti2, boff, rs2, cur2, N);
  place_k<<<(E1 + 255) / 256, 256, 0, stream>>>(src1, dst1, cur1, es1, E1);
  place_k<<<(E2 + 255) / 256, 256, 0, stream>>>(src2, dst2, cur2, es2, E2);

  float* out = (float*)d_out;
  int gemm_grid = (N + 63) / 64;
  int fin_grid = (N + 3) / 4;

  // x buffers per layer: x0=xb0, x1=xbA, x2=xbB, x3=xb0 (x0 dead after t=1)
  u16* xbuf[8];
  xbuf[0] = xb0; xbuf[1] = xbA; xbuf[2] = xbB;
  for (int i = 3; i < 8; ++i) xbuf[i] = xbuf[i - 3];

  for (int t = 0; t < Lnum; ++t) {
    const u16* cur = xbuf[t];
    const u16* prev = (t > 0) ? xbuf[t - 1] : nullptr;
    int fin = (t == Lnum - 1);
    u16* nxt = fin ? nullptr : xbuf[t + 1];
    gemm_mfma_k<<<gemm_grid, 256, 0, stream>>>(cur, wt1 + (size_t)t * 16384, h1,
                                               invo1, a_soft, 2 * t, N);
    if (t > 0)
      gemm_mfma_k<<<gemm_grid, 256, 0, stream>>>(prev, wt2 + (size_t)t * 16384, h2,
                                                 invo2, a_soft, 2 * t + 1, N);
    aggfin_k<<<fin_grid, 256, 0, stream>>>(cur, h1, h2, rs1, es1, rs2, es2,
                                           invi1, invi2, bb + (size_t)t * 128,
                                           nxt, out, N, t > 0 ? 1 : 0, fin);
  }
}